// Round 12
// baseline (290.538 us; speedup 1.0000x reference)
//
#include <hip/hip_runtime.h>
#include <cstdint>
#include <cstddef>

typedef unsigned int u32;
typedef unsigned long long u64;

#define NB 8192
#define BIMG 2
#define WPR (NB / 64)   // 128 u64 words per mask row

// ---------------- workspace layout (bytes) ----------------
#define WS_KCOUNT 0
#define WS_KEYS   256                                // (unused, kept for layout)
#define WS_BOXES  (WS_KEYS + BIMG * NB * 8)          // 131328
#define WS_PROB   (WS_BOXES + BIMG * NB * 16)        // 393472
#define WS_SBOXES (WS_PROB + BIMG * NB * 4)          // 459008
#define WS_SPROB  (WS_SBOXES + BIMG * NB * 16)       // 721152
#define WS_REMV   (WS_SPROB + BIMG * NB * 4)         // 786688 (unused in fast path)
#define WS_MASK   (WS_REMV + BIMG * WPR * 8 + 256)   // 788992 (pad)
#define WS_ROWNZ  (WS_MASK + (size_t)BIMG * NB * WPR * 8)
#define WS_DIAG   (WS_ROWNZ + (size_t)BIMG * NB)         // 8-aligned
#define WS_DIAG2  (WS_DIAG + (size_t)BIMG * NB * 8)      // (unused now)
#define WS_NEEDED (WS_DIAG2 + (size_t)BIMG * NB * 8)     // ~17.9 MB

__device__ inline u64 rdl64(u64 v, int lane) {
  u32 lo = (u32)__builtin_amdgcn_readlane((int)(u32)v, lane);
  u32 hi = (u32)__builtin_amdgcn_readlane((int)(u32)(v >> 32), lane);
  return ((u64)hi << 32) | lo;
}

__device__ inline u64 shflxor64(u64 v, int off) {
  u32 lo = (u32)v, hi = (u32)(v >> 32);
  lo = (u32)__shfl_xor((int)lo, off, 64);
  hi = (u32)__shfl_xor((int)hi, off, 64);
  return ((u64)hi << 32) | lo;
}

// ---------------------------------------------------------------------------
// Kernel 2 (fused decode + sort + gather): one 1024-thread block per image.
// Hybrid bitonic: register / wave-shfl / LDS phases (r11, verified).
// ---------------------------------------------------------------------------
__global__ __launch_bounds__(1024) void sort_kernel(const float* __restrict__ offsets,
                                                    const float* __restrict__ labels,
                                                    const float* __restrict__ anchors,
                                                    float4* __restrict__ boxes,
                                                    float* __restrict__ prob,
                                                    float4* __restrict__ sboxes,
                                                    float* __restrict__ sprob,
                                                    u32* __restrict__ kcount) {
  __shared__ u64 s[NB];                 // 64 KB
  __shared__ u32 scnt;
  const int b = blockIdx.x;
  const int tid = threadIdx.x;
  if (tid == 0) scnt = 0;

  // ---- fused decode (coalesced): element n = q*1024 + tid ----
  u32 lc = 0;
  for (int q = 0; q < 8; ++q) {
    int n = (q << 10) + tid;
    int idx = b * NB + n;
    float logit = labels[idx];
    float p = 1.0f / (1.0f + expf(-logit));
    bool valid = p > 0.5f;

    const float4 an = ((const float4*)anchors)[n];   // x1,y1,x2,y2
    float acx = (an.x + an.z) / 2.0f;
    float acy = (an.y + an.w) / 2.0f;
    float aw = an.z - an.x;
    float ah = an.w - an.y;

    const float4 of = ((const float4*)offsets)[idx]; // gcx,gcy,gw,gh
    float cx = of.x * aw / 10.0f + acx;
    float cy = of.y * ah / 10.0f + acy;
    float w = expf(of.z / 5.0f) * aw;
    float h = expf(of.w / 5.0f) * ah;

    float4 bx;
    bx.x = cx - w / 2.0f;
    bx.y = cy - h / 2.0f;
    bx.z = cx + w / 2.0f;
    bx.w = cy + h / 2.0f;
    boxes[idx] = bx;
    prob[idx] = p;

    u32 e32 = valid ? (__float_as_uint(p) ^ 0x80000000u) : 0u;
    s[n] = ((u64)e32 << 32) | (u32)(~(u32)n);
    lc += valid ? 1u : 0u;
  }
  for (int off = 32; off > 0; off >>= 1) lc += __shfl_down(lc, off, 64);
  __syncthreads();
  if ((tid & 63) == 0) atomicAdd(&scnt, lc);
  __syncthreads();
  if (tid == 0) kcount[b] = scnt;

  u64 e[8];
#pragma unroll
  for (int r = 0; r < 8; ++r) e[r] = s[tid * 8 + r];

  for (int k = 2; k <= NB; k <<= 1) {
    int j = k >> 1;
    if (j >= 512) {
#pragma unroll
      for (int r = 0; r < 8; ++r) s[tid * 8 + r] = e[r];
      __syncthreads();
      for (; j >= 512; j >>= 1) {
        for (int p = tid; p < NB / 2; p += 1024) {
          int i = ((p & ~(j - 1)) << 1) | (p & (j - 1));
          int ixj = i | j;
          u64 a = s[i];
          u64 c = s[ixj];
          bool desc = (i & k) == 0;
          if ((a < c) == desc) { s[i] = c; s[ixj] = a; }
        }
        __syncthreads();
      }
#pragma unroll
      for (int r = 0; r < 8; ++r) e[r] = s[tid * 8 + r];
    }
    for (; j >= 8; j >>= 1) {
      int m = j >> 3;
      bool lowSide = (tid & m) == 0;
      bool descT = ((tid * 8) & k) == 0;
      bool takeMax = (lowSide == descT);
#pragma unroll
      for (int r = 0; r < 8; ++r) {
        u64 p = shflxor64(e[r], m);
        bool sel = (e[r] < p) == takeMax;
        e[r] = sel ? p : e[r];
      }
    }
    for (; j >= 1; j >>= 1) {
#pragma unroll
      for (int r = 0; r < 8; ++r) {
        if ((r & j) == 0) {
          int i = tid * 8 + r;
          bool desc = (i & k) == 0;
          u64 a = e[r];
          u64 c = e[r | j];
          if ((a < c) == desc) { e[r] = c; e[r | j] = a; }
        }
      }
    }
  }

#pragma unroll
  for (int r = 0; r < 8; ++r) s[tid * 8 + r] = e[r];
  __syncthreads();
  for (int q = 0; q < 8; ++q) {
    int i = (q << 10) + tid;
    u64 kk = s[i];
    u32 oi = (u32)(~kk);
    sboxes[(size_t)b * NB + i] = boxes[(size_t)b * NB + oi];
    sprob[(size_t)b * NB + i]  = prob[(size_t)b * NB + oi];
  }
}

// ---------------------------------------------------------------------------
// Kernel 4: overlap bitmask build + per-row nonzero flag + contiguous diag
// band: diag[i] = mask[i][i>>6].
// ---------------------------------------------------------------------------
__global__ __launch_bounds__(256) void mask_kernel(const float4* __restrict__ sboxes,
                                                   const u32* __restrict__ kcount,
                                                   u64* __restrict__ mask,
                                                   unsigned char* __restrict__ rownz,
                                                   u64* __restrict__ diag) {
  const int i = blockIdx.x;       // sorted row
  const int b = blockIdx.y;
  const int K = (int)kcount[b];
  if (i >= K) return;
  const int wave = threadIdx.x >> 6;
  const int lane = threadIdx.x & 63;
  const int tc = i >> 6;
  __shared__ u32 anyf[4];
  const float4* sb = sboxes + (size_t)b * NB;
  const float4 bi = sb[i];
  const float area_i = (bi.z - bi.x) * (bi.w - bi.y);
  u64* mrow = mask + ((size_t)b * NB + i) * WPR;
  bool any = false;
  for (int pass = 0; pass < WPR / 4; ++pass) {
    int w = pass * 4 + wave;
    u64 word = 0;
    bool act = ((w + 1) * 64 > i) && (w * 64 < K);   // uniform per wave
    if (act) {
      int j = w * 64 + lane;
      float4 bj = sb[j];
      float lx = fmaxf(bi.x, bj.x);
      float ly = fmaxf(bi.y, bj.y);
      float rx = fminf(bi.z, bj.z);
      float ry = fminf(bi.w, bj.w);
      float iw = fmaxf(rx - lx, 0.0f);
      float ih = fmaxf(ry - ly, 0.0f);
      float inter = iw * ih;
      float area_j = (bj.z - bj.x) * (bj.w - bj.y);
      float iou = inter / (area_i + area_j - inter);
      bool pred = (j > i) && (j < K) && (iou > 0.5f);
      word = __ballot(pred);
      any = any || (word != 0ull);
    }
    if (lane == 0) {
      if (act) mrow[w] = word;
      if (w == tc) diag[(size_t)b * NB + i] = word;
    }
  }
  if (lane == 0) anyf[wave] = any ? 1u : 0u;
  __syncthreads();
  if (threadIdx.x == 0) {
    u32 a = anyf[0] | anyf[1] | anyf[2] | anyf[3];
    rownz[(size_t)b * NB + i] = (unsigned char)(a ? 1 : 0);
  }
}

// ---------------------------------------------------------------------------
// Kernel 5: BARRIER-FREE producer/consumer greedy scan + fused output.
// 8 waves / image. Wave 0 = resolver; waves 1-7 = row-OR workers.
// Sync via LDS message passing (store -> threadfence_block -> LDS atomic;
// poll with atomic read -> threadfence_block -> read). No __syncthreads in
// the main loop => no forced vmcnt drains; worker loads run 2 chunks ahead
// (all addresses precomputed from nz ballots in the prologue).
// Bit algebra identical to r10 (posts select strictly-future words).
// ---------------------------------------------------------------------------
#define SCAN_WAVES 8
#define NROWW (SCAN_WAVES - 1)
#define MAXROWS 10

__device__ inline void resolve_diag(u64& rc, u64 dw) {
  u64 nzd = __ballot(dw != 0ull) & ~rc;
  while (nzd) {
    int tt = __builtin_ctzll(nzd);
    rc |= rdl64(dw, tt);
    nzd &= ~(1ull << tt) & ~rc;
  }
}

__global__ __launch_bounds__(512) void scan_kernel(const u64* __restrict__ mask,
                                                   const u64* __restrict__ diag,
                                                   const unsigned char* __restrict__ rownz,
                                                   const u32* __restrict__ kcount,
                                                   const float4* __restrict__ sboxes,
                                                   const float* __restrict__ sprob,
                                                   float* __restrict__ out) {
  __shared__ u64 s_remv[WPR];               // finalized rc words
  __shared__ u64 s_nzw[WPR];                // per-chunk nz ballots (prologue)
  __shared__ u64 s_kuArr[WPR];              // published ku per chunk
  __shared__ u64 s_slot[2][NROWW];          // per-wave posted word (ring, depth 2)
  __shared__ int s_postcnt[2];
  __shared__ int s_seq;                     // chunks resolved so far
  const int b = blockIdx.x;
  const int tid = threadIdx.x;
  const int w = tid >> 6;                   // wave id 0..7
  const int l = tid & 63;
  const int K = (int)kcount[b];
  const u64* mb = mask + (size_t)b * NB * WPR;
  const u64* dg = diag + (size_t)b * NB;
  const unsigned char* nzb = rownz + (size_t)b * NB;
  const int NC = min(WPR, (K + 63) >> 6);
  const int NCL = min(NC, 64);

  // ---- prologue: all nz ballots + control init, one barrier ----
  for (int c = w; c < WPR; c += SCAN_WAVES) {
    int i = c * 64 + l;
    unsigned char nz = (c < NC && i < K) ? nzb[i] : (unsigned char)0;
    u64 bal = __ballot(nz != 0);
    if (l == 0) s_nzw[c] = bal;
  }
  if (tid == 0) { s_postcnt[0] = 0; s_postcnt[1] = 0; s_seq = 0; }
  __syncthreads();

  if (w == 0) {
    // ----------------- resolver wave -----------------
    u64 dw0 = 0, dw1 = 0;
    if (NC > 0) dw0 = (l < K) ? dg[l] : 0ull;
    if (NC > 1) dw1 = (64 + l < K) ? dg[64 + l] : 0ull;
    for (int c = 0; c < NC; ++c) {
      u64 dwn = 0;
      if (c + 2 < NC) {
        int i = (c + 2) * 64 + l;
        dwn = (i < K) ? dg[i] : 0ull;
      }
      u64 val = 0;
      if (c > 0) {
        int p = c & 1;
        while (atomicAdd(&s_postcnt[p], 0) < NROWW) __builtin_amdgcn_s_sleep(1);
        __threadfence_block();
#pragma unroll
        for (int q = 0; q < NROWW; ++q) val |= s_slot[p][q];
        atomicExch(&s_postcnt[p], 0);
      }
      int lo = c * 64;
      u64 tail = (lo + 64 <= K) ? 0ull : ((~0ull) << (K - lo));
      u64 rc = val | tail;
      resolve_diag(rc, dw0);
      u64 ku = (~rc) & s_nzw[c];
      if (l == 0) { s_remv[c] = rc; s_kuArr[c] = ku; }
      __threadfence_block();
      if (l == 0) atomicExch(&s_seq, c + 1);
      dw0 = dw1; dw1 = dwn;
    }
  } else {
    // ----------------- row-OR worker wave -----------------
    u64 A[MAXROWS], Ah[MAXROWS], B[MAXROWS], Bh[MAXROWS];
    u64 plo = 0, phi = 0;
    const bool okLo = (l < NCL);
    const bool okHi = (64 + l) < NC;
    const int win = (w - 1) * MAXROWS;

#define LOADW(Lv, Hv, cc) {                                                  \
      u64 kk = ((cc) < NC) ? ((s_nzw[(cc)] >> win) & ((1ull << MAXROWS) - 1ull)) : 0ull; \
      _Pragma("unroll")                                                      \
      for (int q = 0; q < MAXROWS; ++q) {                                    \
        bool has = (kk != 0ull);                                             \
        int tq = has ? __builtin_ctzll(kk) : 0;                              \
        if (has) kk &= kk - 1;                                               \
        Lv[q] = 0; Hv[q] = 0;                                                \
        if (has) {                                                           \
          const u64* rp = mb + (size_t)((cc) * 64 + win + tq) * WPR;         \
          if (okLo) Lv[q] = rp[l];                                           \
          if (okHi) Hv[q] = rp[64 + l];                                      \
        }                                                                    \
      }                                                                      \
    }

#define ACCW(Lv, Hv, cc, kuv) {                                              \
      u64 kk = (s_nzw[(cc)] >> win) & ((1ull << MAXROWS) - 1ull);            \
      _Pragma("unroll")                                                      \
      for (int q = 0; q < MAXROWS; ++q) {                                    \
        bool has = (kk != 0ull);                                             \
        int tq = has ? __builtin_ctzll(kk) : 0;                              \
        if (has) kk &= kk - 1;                                               \
        u64 bit = has ? (1ull << (win + tq)) : 0ull;                         \
        if ((kuv) & bit) { plo |= Lv[q]; phi |= Hv[q]; }                     \
      }                                                                      \
    }

    LOADW(A, Ah, 0)
    LOADW(B, Bh, 1)
    for (int c = 0; c < NC; ++c) {
      while (atomicAdd(&s_seq, 0) < c + 1) __builtin_amdgcn_s_sleep(1);
      __threadfence_block();
      u64 ku = s_kuArr[c];
      if ((c & 1) == 0) { ACCW(A, Ah, c, ku) } else { ACCW(B, Bh, c, ku) }
      // post cumulative word c+1
      int wsel = c + 1;
      u64 v = (wsel < 64) ? plo : phi;
      int pp = wsel & 1;
      if (l == (wsel & 63)) s_slot[pp][w - 1] = v;
      __threadfence_block();
      if (l == 0) atomicAdd(&s_postcnt[pp], 1);
      // prefetch chunk c+2 into the buffer just freed
      if ((c & 1) == 0) { LOADW(A, Ah, c + 2) } else { LOADW(B, Bh, c + 2) }
    }
#undef LOADW
#undef ACCW
  }
  __syncthreads();

  // ---------------- fused output ----------------
  const float4* sbx = sboxes + (size_t)b * NB;
  const float* spb = sprob + (size_t)b * NB;
  for (int p = tid; p < NB; p += 512) {
    bool kp = false;
    if (p < K) {
      u64 wv = s_remv[p >> 6];
      kp = !((wv >> (p & 63)) & 1ull);
    }
    float4 bv = sbx[p];
    if (!kp) { bv.x = 0.0f; bv.y = 0.0f; bv.z = 0.0f; bv.w = 0.0f; }
    ((float4*)out)[(size_t)b * NB + p] = bv;
    out[(size_t)BIMG * NB * 4 + (size_t)b * NB + p] = kp ? spb[p] : 0.0f;
    out[(size_t)BIMG * NB * 5 + (size_t)b * NB + p] = kp ? 1.0f : 0.0f;
  }
}

// ---------------------------------------------------------------------------
// Fallback NMS kernel (used only if workspace is too small)
// ---------------------------------------------------------------------------
__global__ __launch_bounds__(1024) void nms_kernel(const float4* __restrict__ sboxes,
                                                   const float* __restrict__ sprob,
                                                   const u32* __restrict__ kcount,
                                                   float* __restrict__ out) {
  __shared__ float4 sb[NB];
  __shared__ unsigned char flag[NB];
  const int b = blockIdx.x;
  const int t = threadIdx.x;
  const int K = (int)kcount[b];

  for (int p = t; p < NB; p += 1024) {
    sb[p] = sboxes[(size_t)b * NB + p];
    flag[p] = (p < K) ? (unsigned char)0 : (unsigned char)1;
  }
  __syncthreads();

  for (int i = 0; i < K; ++i) {
    if (flag[i]) continue;
    float4 bi = sb[i];
    float area_i = (bi.z - bi.x) * (bi.w - bi.y);
    for (int j = i + 1 + t; j < K; j += 1024) {
      float4 bj = sb[j];
      float lx = fmaxf(bi.x, bj.x);
      float ly = fmaxf(bi.y, bj.y);
      float rx = fminf(bi.z, bj.z);
      float ry = fminf(bi.w, bj.w);
      float iw = fmaxf(rx - lx, 0.0f);
      float ih = fmaxf(ry - ly, 0.0f);
      float inter = iw * ih;
      float area_j = (bj.z - bj.x) * (bj.w - bj.y);
      float iou = inter / (area_i + area_j - inter);
      if (iou > 0.5f) flag[j] = (unsigned char)1;
    }
    __syncthreads();
  }

  float4* oboxes = (float4*)(out) + (size_t)b * NB;
  float* oscores = out + (size_t)BIMG * NB * 4 + (size_t)b * NB;
  float* okeep   = out + (size_t)BIMG * NB * 5 + (size_t)b * NB;
  for (int p = t; p < NB; p += 1024) {
    bool kp = (p < K) && (flag[p] == 0);
    float4 bv = sb[p];
    if (!kp) { bv.x = 0.0f; bv.y = 0.0f; bv.z = 0.0f; bv.w = 0.0f; }
    oboxes[p] = bv;
    oscores[p] = kp ? sprob[(size_t)b * NB + p] : 0.0f;
    okeep[p] = kp ? 1.0f : 0.0f;
  }
}

// ---------------------------------------------------------------------------
extern "C" void kernel_launch(void* const* d_in, const int* in_sizes, int n_in,
                              void* d_out, int out_size, void* d_ws, size_t ws_size,
                              hipStream_t stream) {
  const float* offsets = (const float*)d_in[0];   // [B,N,4] f32
  const float* labels  = (const float*)d_in[1];   // [B,N,1] f32
  const float* anchors = (const float*)d_in[2];   // [N,4]   f32
  float* out = (float*)d_out;

  char* ws = (char*)d_ws;
  u32*    kcount = (u32*)(ws + WS_KCOUNT);
  float4* boxes  = (float4*)(ws + WS_BOXES);
  float*  prob   = (float*)(ws + WS_PROB);
  float4* sboxes = (float4*)(ws + WS_SBOXES);
  float*  sprob  = (float*)(ws + WS_SPROB);

  sort_kernel<<<BIMG, 1024, 0, stream>>>(offsets, labels, anchors,
                                         boxes, prob, sboxes, sprob, kcount);

  if (ws_size >= WS_NEEDED) {
    u64*    mask   = (u64*)(ws + WS_MASK);
    unsigned char* rownz = (unsigned char*)(ws + WS_ROWNZ);
    u64*    diag   = (u64*)(ws + WS_DIAG);

    mask_kernel<<<dim3(NB, BIMG), 256, 0, stream>>>(sboxes, kcount, mask, rownz,
                                                    diag);

    scan_kernel<<<BIMG, 512, 0, stream>>>(mask, diag, rownz, kcount,
                                          sboxes, sprob, out);
  } else {
    nms_kernel<<<BIMG, 1024, 0, stream>>>(sboxes, sprob, kcount, out);
  }
}

// Round 13
// 269.382 us; speedup vs baseline: 1.0785x; 1.0785x over previous
//
#include <hip/hip_runtime.h>
#include <cstdint>
#include <cstddef>

typedef unsigned int u32;
typedef unsigned long long u64;

#define NB 8192
#define BIMG 2
#define WPR (NB / 64)   // 128 u64 words per mask row

// ---------------- workspace layout (bytes) ----------------
#define WS_KCOUNT 0
#define WS_KEYS   256                                // (unused, kept for layout)
#define WS_BOXES  (WS_KEYS + BIMG * NB * 8)          // 131328
#define WS_PROB   (WS_BOXES + BIMG * NB * 16)        // 393472
#define WS_SBOXES (WS_PROB + BIMG * NB * 4)          // 459008
#define WS_SPROB  (WS_SBOXES + BIMG * NB * 16)       // 721152
#define WS_REMV   (WS_SPROB + BIMG * NB * 4)         // 786688 (unused in fast path)
#define WS_MASK   (WS_REMV + BIMG * WPR * 8 + 256)   // 788992 (pad)
#define WS_ROWNZ  (WS_MASK + (size_t)BIMG * NB * WPR * 8)
#define WS_DIAG   (WS_ROWNZ + (size_t)BIMG * NB)         // 8-aligned
#define WS_DIAG2  (WS_DIAG + (size_t)BIMG * NB * 8)
#define WS_NEEDED (WS_DIAG2 + (size_t)BIMG * NB * 8)     // ~17.9 MB

__device__ inline u64 rdl64(u64 v, int lane) {
  u32 lo = (u32)__builtin_amdgcn_readlane((int)(u32)v, lane);
  u32 hi = (u32)__builtin_amdgcn_readlane((int)(u32)(v >> 32), lane);
  return ((u64)hi << 32) | lo;
}

__device__ inline u64 shflxor64(u64 v, int off) {
  u32 lo = (u32)v, hi = (u32)(v >> 32);
  lo = (u32)__shfl_xor((int)lo, off, 64);
  hi = (u32)__shfl_xor((int)hi, off, 64);
  return ((u64)hi << 32) | lo;
}

// ---------------------------------------------------------------------------
// Kernel 2 (fused decode + sort + gather): one 1024-thread block per image.
// Hybrid bitonic: register / wave-shfl / LDS phases (r11, verified).
// ---------------------------------------------------------------------------
__global__ __launch_bounds__(1024) void sort_kernel(const float* __restrict__ offsets,
                                                    const float* __restrict__ labels,
                                                    const float* __restrict__ anchors,
                                                    float4* __restrict__ boxes,
                                                    float* __restrict__ prob,
                                                    float4* __restrict__ sboxes,
                                                    float* __restrict__ sprob,
                                                    u32* __restrict__ kcount) {
  __shared__ u64 s[NB];                 // 64 KB
  __shared__ u32 scnt;
  const int b = blockIdx.x;
  const int tid = threadIdx.x;
  if (tid == 0) scnt = 0;

  // ---- fused decode (coalesced): element n = q*1024 + tid ----
  u32 lc = 0;
  for (int q = 0; q < 8; ++q) {
    int n = (q << 10) + tid;
    int idx = b * NB + n;
    float logit = labels[idx];
    float p = 1.0f / (1.0f + expf(-logit));
    bool valid = p > 0.5f;

    const float4 an = ((const float4*)anchors)[n];   // x1,y1,x2,y2
    float acx = (an.x + an.z) / 2.0f;
    float acy = (an.y + an.w) / 2.0f;
    float aw = an.z - an.x;
    float ah = an.w - an.y;

    const float4 of = ((const float4*)offsets)[idx]; // gcx,gcy,gw,gh
    float cx = of.x * aw / 10.0f + acx;
    float cy = of.y * ah / 10.0f + acy;
    float w = expf(of.z / 5.0f) * aw;
    float h = expf(of.w / 5.0f) * ah;

    float4 bx;
    bx.x = cx - w / 2.0f;
    bx.y = cy - h / 2.0f;
    bx.z = cx + w / 2.0f;
    bx.w = cy + h / 2.0f;
    boxes[idx] = bx;
    prob[idx] = p;

    u32 e32 = valid ? (__float_as_uint(p) ^ 0x80000000u) : 0u;
    s[n] = ((u64)e32 << 32) | (u32)(~(u32)n);
    lc += valid ? 1u : 0u;
  }
  for (int off = 32; off > 0; off >>= 1) lc += __shfl_down(lc, off, 64);
  __syncthreads();
  if ((tid & 63) == 0) atomicAdd(&scnt, lc);
  __syncthreads();
  if (tid == 0) kcount[b] = scnt;

  u64 e[8];
#pragma unroll
  for (int r = 0; r < 8; ++r) e[r] = s[tid * 8 + r];

  for (int k = 2; k <= NB; k <<= 1) {
    int j = k >> 1;
    if (j >= 512) {
#pragma unroll
      for (int r = 0; r < 8; ++r) s[tid * 8 + r] = e[r];
      __syncthreads();
      for (; j >= 512; j >>= 1) {
        for (int p = tid; p < NB / 2; p += 1024) {
          int i = ((p & ~(j - 1)) << 1) | (p & (j - 1));
          int ixj = i | j;
          u64 a = s[i];
          u64 c = s[ixj];
          bool desc = (i & k) == 0;
          if ((a < c) == desc) { s[i] = c; s[ixj] = a; }
        }
        __syncthreads();
      }
#pragma unroll
      for (int r = 0; r < 8; ++r) e[r] = s[tid * 8 + r];
    }
    for (; j >= 8; j >>= 1) {
      int m = j >> 3;
      bool lowSide = (tid & m) == 0;
      bool descT = ((tid * 8) & k) == 0;
      bool takeMax = (lowSide == descT);
#pragma unroll
      for (int r = 0; r < 8; ++r) {
        u64 p = shflxor64(e[r], m);
        bool sel = (e[r] < p) == takeMax;
        e[r] = sel ? p : e[r];
      }
    }
    for (; j >= 1; j >>= 1) {
#pragma unroll
      for (int r = 0; r < 8; ++r) {
        if ((r & j) == 0) {
          int i = tid * 8 + r;
          bool desc = (i & k) == 0;
          u64 a = e[r];
          u64 c = e[r | j];
          if ((a < c) == desc) { e[r] = c; e[r | j] = a; }
        }
      }
    }
  }

#pragma unroll
  for (int r = 0; r < 8; ++r) s[tid * 8 + r] = e[r];
  __syncthreads();
  for (int q = 0; q < 8; ++q) {
    int i = (q << 10) + tid;
    u64 kk = s[i];
    u32 oi = (u32)(~kk);
    sboxes[(size_t)b * NB + i] = boxes[(size_t)b * NB + oi];
    sprob[(size_t)b * NB + i]  = prob[(size_t)b * NB + oi];
  }
}

// ---------------------------------------------------------------------------
// Kernel 4: overlap bitmask build — PERSISTENT blocks. Grid 256 x BIMG; each
// block loops rows i = bid, bid+256, ... (interleaved for balance). Per-row
// work, guards and mask/diag/diag2/rownz writes identical to r11.
// ---------------------------------------------------------------------------
__global__ __launch_bounds__(256) void mask_kernel(const float4* __restrict__ sboxes,
                                                   const u32* __restrict__ kcount,
                                                   u64* __restrict__ mask,
                                                   unsigned char* __restrict__ rownz,
                                                   u64* __restrict__ diag,
                                                   u64* __restrict__ diag2) {
  const int b = blockIdx.y;
  const int K = (int)kcount[b];
  const int wave = threadIdx.x >> 6;
  const int lane = threadIdx.x & 63;
  __shared__ u32 anyf[4];
  const float4* sb = sboxes + (size_t)b * NB;

  for (int i = blockIdx.x; i < K; i += gridDim.x) {
    const int tc = i >> 6;
    const float4 bi = sb[i];
    const float area_i = (bi.z - bi.x) * (bi.w - bi.y);
    u64* mrow = mask + ((size_t)b * NB + i) * WPR;
    bool any = false;
    for (int pass = tc >> 2; pass < WPR / 4; ++pass) {   // words < tc are inert
      int w = pass * 4 + wave;
      u64 word = 0;
      bool act = ((w + 1) * 64 > i) && (w * 64 < K);     // uniform per wave
      if (act) {
        int j = w * 64 + lane;
        float4 bj = sb[j];
        float lx = fmaxf(bi.x, bj.x);
        float ly = fmaxf(bi.y, bj.y);
        float rx = fminf(bi.z, bj.z);
        float ry = fminf(bi.w, bj.w);
        float iw = fmaxf(rx - lx, 0.0f);
        float ih = fmaxf(ry - ly, 0.0f);
        float inter = iw * ih;
        float area_j = (bj.z - bj.x) * (bj.w - bj.y);
        float iou = inter / (area_i + area_j - inter);
        bool pred = (j > i) && (j < K) && (iou > 0.5f);
        word = __ballot(pred);
        any = any || (word != 0ull);
      }
      if (lane == 0) {
        if (act) mrow[w] = word;
        if (w == tc)          diag[(size_t)b * NB + i]  = word;
        else if (w == tc + 1) diag2[(size_t)b * NB + i] = word;  // 0 if !act
      }
    }
    if (lane == 0) anyf[wave] = any ? 1u : 0u;
    __syncthreads();
    if (threadIdx.x == 0) {
      u32 a = anyf[0] | anyf[1] | anyf[2] | anyf[3];
      rownz[(size_t)b * NB + i] = (unsigned char)(a ? 1 : 0);
    }
    __syncthreads();    // protect anyf reuse on next row
  }
}

// ---------------------------------------------------------------------------
// Kernel 5: PAIRED chunked greedy scan + fused output (r10/r11, verified 92us).
// ---------------------------------------------------------------------------
#define SCAN_WAVES 8
#define MAXROWS 10

__device__ inline void resolve_diag(u64& rc, u64 dw) {
  u64 nzd = __ballot(dw != 0ull) & ~rc;
  while (nzd) {
    int tt = __builtin_ctzll(nzd);
    rc |= rdl64(dw, tt);
    nzd &= ~(1ull << tt) & ~rc;
  }
}

__global__ __launch_bounds__(512) void scan_kernel(const u64* __restrict__ mask,
                                                   const u64* __restrict__ diag,
                                                   const u64* __restrict__ diag2,
                                                   const unsigned char* __restrict__ rownz,
                                                   const u32* __restrict__ kcount,
                                                   const float4* __restrict__ sboxes,
                                                   const float* __restrict__ sprob,
                                                   float* __restrict__ out) {
  __shared__ u64 s_remv[WPR];               // finalized rc words (1 KB)
  __shared__ u64 s_slotE[2][SCAN_WAVES];    // posts of word 2t+2
  __shared__ u64 s_slotO[2][SCAN_WAVES];    // posts of word 2t+3
  __shared__ u64 s_kuA, s_kuB, s_nzwA, s_nzwB;
  const int b = blockIdx.x;
  const int tid = threadIdx.x;
  const int w = tid >> 6;                   // wave id 0..7
  const int l = tid & 63;
  const int K = (int)kcount[b];
  const u64* mb = mask + (size_t)b * NB * WPR;
  const u64* dg = diag + (size_t)b * NB;
  const u64* dg2 = diag2 + (size_t)b * NB;
  const unsigned char* nzb = rownz + (size_t)b * NB;
  const int NC = min(WPR, (K + 63) >> 6);
  const int NCL = min(NC, 64);
  const int NP = (NC + 1) >> 1;             // chunk pairs

  if (tid < 2 * SCAN_WAVES) { ((u64*)s_slotE)[tid] = 0; ((u64*)s_slotO)[tid] = 0; }

  u64 plo = 0, phi = 0;
  const bool okLo = (l < NCL);
  const bool okHi = (64 + l) < NC;
  u64 LA[MAXROWS], HA[MAXROWS], LB[MAXROWS], HB[MAXROWS];
  u64 bqA[MAXROWS], bqB[MAXROWS];
  u64 dwA = 0, dwB = 0, cw = 0;
  unsigned char nzcA = 0, nzcB = 0;

  if (w == 0 && NP > 0) {
    int rA = l, rB = 64 + l;
    dwA = (rA < K) ? dg[rA] : 0ull;
    dwB = (rB < K) ? dg[rB] : 0ull;
    cw  = (rA < K) ? dg2[rA] : 0ull;
    nzcA = (rA < K) ? nzb[rA] : (unsigned char)0;
    nzcB = (rB < K) ? nzb[rB] : (unsigned char)0;
    u64 a0 = __ballot(nzcA != 0), b0 = __ballot(nzcB != 0);
    if (l == 0) { s_nzwA = a0; s_nzwB = b0; }
  }
  __syncthreads();

  for (int t = 0; t < NP; ++t) {
    const int cA = 2 * t, cB = 2 * t + 1;
    const bool hasB = (cB < NC);
    // ---------------- phase 1 ----------------
    if (w == 0) {
      u64 dwA_n = 0, dwB_n = 0, cw_n = 0;
      unsigned char nzA_n = 0, nzB_n = 0;
      if (t + 1 < NP) {
        int rA = (t + 1) * 128 + l, rB = (t + 1) * 128 + 64 + l;
        dwA_n = (rA < K) ? dg[rA] : 0ull;
        dwB_n = (rB < K) ? dg[rB] : 0ull;
        cw_n  = (rA < K) ? dg2[rA] : 0ull;
        nzA_n = (rA < K) ? nzb[rA] : (unsigned char)0;
        nzB_n = (rB < K) ? nzb[rB] : (unsigned char)0;
      }
      int pr = (t + 1) & 1;
      u64 valA = s_slotE[pr][l & (SCAN_WAVES - 1)];
      u64 valB = s_slotO[pr][l & (SCAN_WAVES - 1)];
#pragma unroll
      for (int off = 1; off < SCAN_WAVES; off <<= 1) {
        valA |= shflxor64(valA, off);
        valB |= shflxor64(valB, off);
      }
      int loA = cA * 64;
      u64 tailA = (loA + 64 <= K) ? 0ull : ((~0ull) << (K - loA));
      u64 rcA = valA | tailA;
      u64 nzwA = __ballot(nzcA != 0);
      resolve_diag(rcA, dwA);
      u64 kuA = (~rcA) & nzwA;
      u64 m = ((~rcA >> l) & 1ull) ? cw : 0ull;
#pragma unroll
      for (int off = 32; off > 0; off >>= 1) m |= shflxor64(m, off);
      u64 rcB = ~0ull, kuB = 0;
      if (hasB) {
        int loB = cB * 64;
        u64 tailB = (loB + 64 <= K) ? 0ull : ((~0ull) << (K - loB));
        rcB = valB | tailB | m;
        u64 nzwB = __ballot(nzcB != 0);
        resolve_diag(rcB, dwB);
        kuB = (~rcB) & nzwB;
      }
      if (l == 0) {
        s_remv[cA] = rcA;
        if (hasB) s_remv[cB] = rcB;
        s_kuA = kuA; s_kuB = kuB;
      }
      dwA = dwA_n; dwB = dwB_n; cw = cw_n; nzcA = nzA_n; nzcB = nzB_n;
    } else {
      u64 kkA = (s_nzwA >> ((w - 1) * MAXROWS)) & ((1ull << MAXROWS) - 1ull);
      u64 kkB = (s_nzwB >> ((w - 1) * MAXROWS)) & ((1ull << MAXROWS) - 1ull);
#pragma unroll
      for (int q = 0; q < MAXROWS; ++q) {
        bool hA = (kkA != 0ull);
        int tA = hA ? __builtin_ctzll(kkA) : 0;
        if (hA) kkA &= kkA - 1;
        bqA[q] = hA ? (1ull << ((w - 1) * MAXROWS + tA)) : 0ull;
        LA[q] = 0; HA[q] = 0;
        if (hA) {
          const u64* rp = mb + (size_t)(cA * 64 + (w - 1) * MAXROWS + tA) * WPR;
          if (okLo) LA[q] = rp[l];
          if (okHi) HA[q] = rp[64 + l];
        }
        bool hB = (kkB != 0ull);
        int tB = hB ? __builtin_ctzll(kkB) : 0;
        if (hB) kkB &= kkB - 1;
        bqB[q] = hB ? (1ull << ((w - 1) * MAXROWS + tB)) : 0ull;
        LB[q] = 0; HB[q] = 0;
        if (hB) {
          const u64* rp = mb + (size_t)(cB * 64 + (w - 1) * MAXROWS + tB) * WPR;
          if (okLo) LB[q] = rp[l];
          if (okHi) HB[q] = rp[64 + l];
        }
      }
    }
    __syncthreads();                     // barrier A

    // ---------------- phase 2 (register/LDS only) ----------------
    if (w == 0) {
      u64 a1 = __ballot(nzcA != 0), b1 = __ballot(nzcB != 0);
      if (l == 0) { s_nzwA = a1; s_nzwB = b1; }
    } else {
      u64 kuA = s_kuA, kuB = s_kuB;
#pragma unroll
      for (int q = 0; q < MAXROWS; ++q) {
        if (kuA & bqA[q]) { plo |= LA[q]; phi |= HA[q]; }
        if (kuB & bqB[q]) { plo |= LB[q]; phi |= HB[q]; }
      }
      int wE = cA + 2, wO = cA + 3;
      u64 vE = (wE < 64) ? plo : phi;
      if (l == (wE & 63)) s_slotE[t & 1][w] = vE;
      u64 vO = (wO < 64) ? plo : phi;
      if (l == (wO & 63)) s_slotO[t & 1][w] = vO;
    }
    __syncthreads();                     // barrier B
  }

  // ---------------- fused output ----------------
  const float4* sbx = sboxes + (size_t)b * NB;
  const float* spb = sprob + (size_t)b * NB;
  for (int p = tid; p < NB; p += 512) {
    bool kp = false;
    if (p < K) {
      u64 wv = s_remv[p >> 6];
      kp = !((wv >> (p & 63)) & 1ull);
    }
    float4 bv = sbx[p];
    if (!kp) { bv.x = 0.0f; bv.y = 0.0f; bv.z = 0.0f; bv.w = 0.0f; }
    ((float4*)out)[(size_t)b * NB + p] = bv;
    out[(size_t)BIMG * NB * 4 + (size_t)b * NB + p] = kp ? spb[p] : 0.0f;
    out[(size_t)BIMG * NB * 5 + (size_t)b * NB + p] = kp ? 1.0f : 0.0f;
  }
}

// ---------------------------------------------------------------------------
// Fallback NMS kernel (used only if workspace is too small)
// ---------------------------------------------------------------------------
__global__ __launch_bounds__(1024) void nms_kernel(const float4* __restrict__ sboxes,
                                                   const float* __restrict__ sprob,
                                                   const u32* __restrict__ kcount,
                                                   float* __restrict__ out) {
  __shared__ float4 sb[NB];
  __shared__ unsigned char flag[NB];
  const int b = blockIdx.x;
  const int t = threadIdx.x;
  const int K = (int)kcount[b];

  for (int p = t; p < NB; p += 1024) {
    sb[p] = sboxes[(size_t)b * NB + p];
    flag[p] = (p < K) ? (unsigned char)0 : (unsigned char)1;
  }
  __syncthreads();

  for (int i = 0; i < K; ++i) {
    if (flag[i]) continue;
    float4 bi = sb[i];
    float area_i = (bi.z - bi.x) * (bi.w - bi.y);
    for (int j = i + 1 + t; j < K; j += 1024) {
      float4 bj = sb[j];
      float lx = fmaxf(bi.x, bj.x);
      float ly = fmaxf(bi.y, bj.y);
      float rx = fminf(bi.z, bj.z);
      float ry = fminf(bi.w, bj.w);
      float iw = fmaxf(rx - lx, 0.0f);
      float ih = fmaxf(ry - ly, 0.0f);
      float inter = iw * ih;
      float area_j = (bj.z - bj.x) * (bj.w - bj.y);
      float iou = inter / (area_i + area_j - inter);
      if (iou > 0.5f) flag[j] = (unsigned char)1;
    }
    __syncthreads();
  }

  float4* oboxes = (float4*)(out) + (size_t)b * NB;
  float* oscores = out + (size_t)BIMG * NB * 4 + (size_t)b * NB;
  float* okeep   = out + (size_t)BIMG * NB * 5 + (size_t)b * NB;
  for (int p = t; p < NB; p += 1024) {
    bool kp = (p < K) && (flag[p] == 0);
    float4 bv = sb[p];
    if (!kp) { bv.x = 0.0f; bv.y = 0.0f; bv.z = 0.0f; bv.w = 0.0f; }
    oboxes[p] = bv;
    oscores[p] = kp ? sprob[(size_t)b * NB + p] : 0.0f;
    okeep[p] = kp ? 1.0f : 0.0f;
  }
}

// ---------------------------------------------------------------------------
extern "C" void kernel_launch(void* const* d_in, const int* in_sizes, int n_in,
                              void* d_out, int out_size, void* d_ws, size_t ws_size,
                              hipStream_t stream) {
  const float* offsets = (const float*)d_in[0];   // [B,N,4] f32
  const float* labels  = (const float*)d_in[1];   // [B,N,1] f32
  const float* anchors = (const float*)d_in[2];   // [N,4]   f32
  float* out = (float*)d_out;

  char* ws = (char*)d_ws;
  u32*    kcount = (u32*)(ws + WS_KCOUNT);
  float4* boxes  = (float4*)(ws + WS_BOXES);
  float*  prob   = (float*)(ws + WS_PROB);
  float4* sboxes = (float4*)(ws + WS_SBOXES);
  float*  sprob  = (float*)(ws + WS_SPROB);

  sort_kernel<<<BIMG, 1024, 0, stream>>>(offsets, labels, anchors,
                                         boxes, prob, sboxes, sprob, kcount);

  if (ws_size >= WS_NEEDED) {
    u64*    mask   = (u64*)(ws + WS_MASK);
    unsigned char* rownz = (unsigned char*)(ws + WS_ROWNZ);
    u64*    diag   = (u64*)(ws + WS_DIAG);
    u64*    diag2  = (u64*)(ws + WS_DIAG2);

    mask_kernel<<<dim3(256, BIMG), 256, 0, stream>>>(sboxes, kcount, mask, rownz,
                                                     diag, diag2);

    scan_kernel<<<BIMG, 512, 0, stream>>>(mask, diag, diag2, rownz, kcount,
                                          sboxes, sprob, out);
  } else {
    nms_kernel<<<BIMG, 1024, 0, stream>>>(sboxes, sprob, kcount, out);
  }
}

// Round 14
// 245.256 us; speedup vs baseline: 1.1846x; 1.0984x over previous
//
#include <hip/hip_runtime.h>
#include <cstdint>
#include <cstddef>

typedef unsigned int u32;
typedef unsigned long long u64;

#define NB 8192
#define BIMG 2
#define WPR (NB / 64)   // 128 u64 words per mask row

// ---------------- workspace layout (bytes) ----------------
#define WS_KCOUNT 0
#define WS_KEYS   256                                // (unused, kept for layout)
#define WS_BOXES  (WS_KEYS + BIMG * NB * 8)          // 131328
#define WS_PROB   (WS_BOXES + BIMG * NB * 16)        // 393472
#define WS_SBOXES (WS_PROB + BIMG * NB * 4)          // 459008
#define WS_SPROB  (WS_SBOXES + BIMG * NB * 16)       // 721152
#define WS_REMV   (WS_SPROB + BIMG * NB * 4)         // 786688 (unused in fast path)
#define WS_MASK   (WS_REMV + BIMG * WPR * 8 + 256)   // 788992 (pad)
#define WS_ROWNZ  (WS_MASK + (size_t)BIMG * NB * WPR * 8)
#define WS_DIAG   (WS_ROWNZ + (size_t)BIMG * NB)         // 8-aligned
#define WS_DIAG2  (WS_DIAG + (size_t)BIMG * NB * 8)
#define WS_NEEDED (WS_DIAG2 + (size_t)BIMG * NB * 8)     // ~17.9 MB

__device__ inline u64 rdl64(u64 v, int lane) {
  u32 lo = (u32)__builtin_amdgcn_readlane((int)(u32)v, lane);
  u32 hi = (u32)__builtin_amdgcn_readlane((int)(u32)(v >> 32), lane);
  return ((u64)hi << 32) | lo;
}

__device__ inline u64 shflxor64(u64 v, int off) {
  u32 lo = (u32)v, hi = (u32)(v >> 32);
  lo = (u32)__shfl_xor((int)lo, off, 64);
  hi = (u32)__shfl_xor((int)hi, off, 64);
  return ((u64)hi << 32) | lo;
}

// ---------------------------------------------------------------------------
// Kernel 2 (fused decode + sort + gather): one 1024-thread block per image.
// Hybrid bitonic: register / wave-shfl / LDS phases (r11, verified).
// ---------------------------------------------------------------------------
__global__ __launch_bounds__(1024) void sort_kernel(const float* __restrict__ offsets,
                                                    const float* __restrict__ labels,
                                                    const float* __restrict__ anchors,
                                                    float4* __restrict__ boxes,
                                                    float* __restrict__ prob,
                                                    float4* __restrict__ sboxes,
                                                    float* __restrict__ sprob,
                                                    u32* __restrict__ kcount) {
  __shared__ u64 s[NB];                 // 64 KB
  __shared__ u32 scnt;
  const int b = blockIdx.x;
  const int tid = threadIdx.x;
  if (tid == 0) scnt = 0;

  // ---- fused decode (coalesced): element n = q*1024 + tid ----
  u32 lc = 0;
  for (int q = 0; q < 8; ++q) {
    int n = (q << 10) + tid;
    int idx = b * NB + n;
    float logit = labels[idx];
    float p = 1.0f / (1.0f + expf(-logit));
    bool valid = p > 0.5f;

    const float4 an = ((const float4*)anchors)[n];   // x1,y1,x2,y2
    float acx = (an.x + an.z) / 2.0f;
    float acy = (an.y + an.w) / 2.0f;
    float aw = an.z - an.x;
    float ah = an.w - an.y;

    const float4 of = ((const float4*)offsets)[idx]; // gcx,gcy,gw,gh
    float cx = of.x * aw / 10.0f + acx;
    float cy = of.y * ah / 10.0f + acy;
    float w = expf(of.z / 5.0f) * aw;
    float h = expf(of.w / 5.0f) * ah;

    float4 bx;
    bx.x = cx - w / 2.0f;
    bx.y = cy - h / 2.0f;
    bx.z = cx + w / 2.0f;
    bx.w = cy + h / 2.0f;
    boxes[idx] = bx;
    prob[idx] = p;

    u32 e32 = valid ? (__float_as_uint(p) ^ 0x80000000u) : 0u;
    s[n] = ((u64)e32 << 32) | (u32)(~(u32)n);
    lc += valid ? 1u : 0u;
  }
  for (int off = 32; off > 0; off >>= 1) lc += __shfl_down(lc, off, 64);
  __syncthreads();
  if ((tid & 63) == 0) atomicAdd(&scnt, lc);
  __syncthreads();
  if (tid == 0) kcount[b] = scnt;

  u64 e[8];
#pragma unroll
  for (int r = 0; r < 8; ++r) e[r] = s[tid * 8 + r];

  for (int k = 2; k <= NB; k <<= 1) {
    int j = k >> 1;
    if (j >= 512) {
#pragma unroll
      for (int r = 0; r < 8; ++r) s[tid * 8 + r] = e[r];
      __syncthreads();
      for (; j >= 512; j >>= 1) {
        for (int p = tid; p < NB / 2; p += 1024) {
          int i = ((p & ~(j - 1)) << 1) | (p & (j - 1));
          int ixj = i | j;
          u64 a = s[i];
          u64 c = s[ixj];
          bool desc = (i & k) == 0;
          if ((a < c) == desc) { s[i] = c; s[ixj] = a; }
        }
        __syncthreads();
      }
#pragma unroll
      for (int r = 0; r < 8; ++r) e[r] = s[tid * 8 + r];
    }
    for (; j >= 8; j >>= 1) {
      int m = j >> 3;
      bool lowSide = (tid & m) == 0;
      bool descT = ((tid * 8) & k) == 0;
      bool takeMax = (lowSide == descT);
#pragma unroll
      for (int r = 0; r < 8; ++r) {
        u64 p = shflxor64(e[r], m);
        bool sel = (e[r] < p) == takeMax;
        e[r] = sel ? p : e[r];
      }
    }
    for (; j >= 1; j >>= 1) {
#pragma unroll
      for (int r = 0; r < 8; ++r) {
        if ((r & j) == 0) {
          int i = tid * 8 + r;
          bool desc = (i & k) == 0;
          u64 a = e[r];
          u64 c = e[r | j];
          if ((a < c) == desc) { e[r] = c; e[r | j] = a; }
        }
      }
    }
  }

#pragma unroll
  for (int r = 0; r < 8; ++r) s[tid * 8 + r] = e[r];
  __syncthreads();
  for (int q = 0; q < 8; ++q) {
    int i = (q << 10) + tid;
    u64 kk = s[i];
    u32 oi = (u32)(~kk);
    sboxes[(size_t)b * NB + i] = boxes[(size_t)b * NB + oi];
    sprob[(size_t)b * NB + i]  = prob[(size_t)b * NB + oi];
  }
}

// ---------------------------------------------------------------------------
// Kernel 4: overlap bitmask build — TILED with LDS row-broadcast.
// Block = 64 consecutive sorted rows [i0, i0+64); grid (NB/64) x BIMG, 512 thr.
// Each wave owns column-words w = tc+wv, tc+wv+8, ...; lane loads its bj ONCE
// per word and reuses it across all 64 rows (s_bi broadcast). Lane r keeps
// row r's ballot -> coalesced-ish per-lane stores. Write-set, IoU expression
// and predicate identical to the proven r12 mask.
// ---------------------------------------------------------------------------
#define MTILE 64

__global__ __launch_bounds__(512) void mask_kernel(const float4* __restrict__ sboxes,
                                                   const u32* __restrict__ kcount,
                                                   u64* __restrict__ mask,
                                                   unsigned char* __restrict__ rownz,
                                                   u64* __restrict__ diag,
                                                   u64* __restrict__ diag2) {
  const int b = blockIdx.y;
  const int K = (int)kcount[b];
  const int i0 = blockIdx.x * MTILE;
  if (i0 >= K) return;
  const int wv = threadIdx.x >> 6;     // wave 0..7
  const int lane = threadIdx.x & 63;
  __shared__ float4 s_bi[MTILE];
  __shared__ u32 s_any[MTILE];
  if (threadIdx.x < MTILE) {
    s_bi[threadIdx.x] = sboxes[(size_t)b * NB + i0 + threadIdx.x];
    s_any[threadIdx.x] = 0;
  }
  __syncthreads();

  const int tc = i0 >> 6;
  const int NC = min(WPR, (K + 63) >> 6);
  const int irow = i0 + lane;          // row owned by this lane (for stores)
  u64* mbase = mask + (size_t)b * NB * WPR;
  u32 anyacc = 0;

  for (int w = tc + wv; w < NC; w += 8) {
    int j = w * 64 + lane;
    float4 bj = sboxes[(size_t)b * NB + j];
    float area_j = (bj.z - bj.x) * (bj.w - bj.y);
    u64 myword = 0;
    for (int r = 0; r < MTILE; ++r) {
      float4 bi = s_bi[r];
      float area_i = (bi.z - bi.x) * (bi.w - bi.y);
      float lx = fmaxf(bi.x, bj.x);
      float ly = fmaxf(bi.y, bj.y);
      float rx = fminf(bi.z, bj.z);
      float ry = fminf(bi.w, bj.w);
      float iw = fmaxf(rx - lx, 0.0f);
      float ih = fmaxf(ry - ly, 0.0f);
      float inter = iw * ih;
      float iou = inter / (area_i + area_j - inter);
      bool pred = (j > i0 + r) && (j < K) && (iou > 0.5f);
      u64 bal = __ballot(pred);
      if (lane == r) myword = bal;
    }
    if (irow < K) {
      mbase[(size_t)irow * WPR + w] = myword;
      if (w == tc)      diag[(size_t)b * NB + irow]  = myword;
      if (w == tc + 1)  diag2[(size_t)b * NB + irow] = myword;
    }
    anyacc |= (myword != 0ull) ? 1u : 0u;
  }
  if (anyacc) atomicOr(&s_any[lane], 1u);
  __syncthreads();
  if (threadIdx.x < MTILE) {
    int i = i0 + threadIdx.x;
    if (i < K) rownz[(size_t)b * NB + i] = (unsigned char)(s_any[threadIdx.x] ? 1 : 0);
  }
}

// ---------------------------------------------------------------------------
// Kernel 5: PAIRED chunked greedy scan + fused output (r10/r12, verified 92us).
// ---------------------------------------------------------------------------
#define SCAN_WAVES 8
#define MAXROWS 10

__device__ inline void resolve_diag(u64& rc, u64 dw) {
  u64 nzd = __ballot(dw != 0ull) & ~rc;
  while (nzd) {
    int tt = __builtin_ctzll(nzd);
    rc |= rdl64(dw, tt);
    nzd &= ~(1ull << tt) & ~rc;
  }
}

__global__ __launch_bounds__(512) void scan_kernel(const u64* __restrict__ mask,
                                                   const u64* __restrict__ diag,
                                                   const u64* __restrict__ diag2,
                                                   const unsigned char* __restrict__ rownz,
                                                   const u32* __restrict__ kcount,
                                                   const float4* __restrict__ sboxes,
                                                   const float* __restrict__ sprob,
                                                   float* __restrict__ out) {
  __shared__ u64 s_remv[WPR];               // finalized rc words (1 KB)
  __shared__ u64 s_slotE[2][SCAN_WAVES];    // posts of word 2t+2
  __shared__ u64 s_slotO[2][SCAN_WAVES];    // posts of word 2t+3
  __shared__ u64 s_kuA, s_kuB, s_nzwA, s_nzwB;
  const int b = blockIdx.x;
  const int tid = threadIdx.x;
  const int w = tid >> 6;                   // wave id 0..7
  const int l = tid & 63;
  const int K = (int)kcount[b];
  const u64* mb = mask + (size_t)b * NB * WPR;
  const u64* dg = diag + (size_t)b * NB;
  const u64* dg2 = diag2 + (size_t)b * NB;
  const unsigned char* nzb = rownz + (size_t)b * NB;
  const int NC = min(WPR, (K + 63) >> 6);
  const int NCL = min(NC, 64);
  const int NP = (NC + 1) >> 1;             // chunk pairs

  if (tid < 2 * SCAN_WAVES) { ((u64*)s_slotE)[tid] = 0; ((u64*)s_slotO)[tid] = 0; }

  u64 plo = 0, phi = 0;
  const bool okLo = (l < NCL);
  const bool okHi = (64 + l) < NC;
  u64 LA[MAXROWS], HA[MAXROWS], LB[MAXROWS], HB[MAXROWS];
  u64 bqA[MAXROWS], bqB[MAXROWS];
  u64 dwA = 0, dwB = 0, cw = 0;
  unsigned char nzcA = 0, nzcB = 0;

  if (w == 0 && NP > 0) {
    int rA = l, rB = 64 + l;
    dwA = (rA < K) ? dg[rA] : 0ull;
    dwB = (rB < K) ? dg[rB] : 0ull;
    cw  = (rA < K) ? dg2[rA] : 0ull;
    nzcA = (rA < K) ? nzb[rA] : (unsigned char)0;
    nzcB = (rB < K) ? nzb[rB] : (unsigned char)0;
    u64 a0 = __ballot(nzcA != 0), b0 = __ballot(nzcB != 0);
    if (l == 0) { s_nzwA = a0; s_nzwB = b0; }
  }
  __syncthreads();

  for (int t = 0; t < NP; ++t) {
    const int cA = 2 * t, cB = 2 * t + 1;
    const bool hasB = (cB < NC);
    // ---------------- phase 1 ----------------
    if (w == 0) {
      u64 dwA_n = 0, dwB_n = 0, cw_n = 0;
      unsigned char nzA_n = 0, nzB_n = 0;
      if (t + 1 < NP) {
        int rA = (t + 1) * 128 + l, rB = (t + 1) * 128 + 64 + l;
        dwA_n = (rA < K) ? dg[rA] : 0ull;
        dwB_n = (rB < K) ? dg[rB] : 0ull;
        cw_n  = (rA < K) ? dg2[rA] : 0ull;
        nzA_n = (rA < K) ? nzb[rA] : (unsigned char)0;
        nzB_n = (rB < K) ? nzb[rB] : (unsigned char)0;
      }
      int pr = (t + 1) & 1;
      u64 valA = s_slotE[pr][l & (SCAN_WAVES - 1)];
      u64 valB = s_slotO[pr][l & (SCAN_WAVES - 1)];
#pragma unroll
      for (int off = 1; off < SCAN_WAVES; off <<= 1) {
        valA |= shflxor64(valA, off);
        valB |= shflxor64(valB, off);
      }
      int loA = cA * 64;
      u64 tailA = (loA + 64 <= K) ? 0ull : ((~0ull) << (K - loA));
      u64 rcA = valA | tailA;
      u64 nzwA = __ballot(nzcA != 0);
      resolve_diag(rcA, dwA);
      u64 kuA = (~rcA) & nzwA;
      u64 m = ((~rcA >> l) & 1ull) ? cw : 0ull;
#pragma unroll
      for (int off = 32; off > 0; off >>= 1) m |= shflxor64(m, off);
      u64 rcB = ~0ull, kuB = 0;
      if (hasB) {
        int loB = cB * 64;
        u64 tailB = (loB + 64 <= K) ? 0ull : ((~0ull) << (K - loB));
        rcB = valB | tailB | m;
        u64 nzwB = __ballot(nzcB != 0);
        resolve_diag(rcB, dwB);
        kuB = (~rcB) & nzwB;
      }
      if (l == 0) {
        s_remv[cA] = rcA;
        if (hasB) s_remv[cB] = rcB;
        s_kuA = kuA; s_kuB = kuB;
      }
      dwA = dwA_n; dwB = dwB_n; cw = cw_n; nzcA = nzA_n; nzcB = nzB_n;
    } else {
      u64 kkA = (s_nzwA >> ((w - 1) * MAXROWS)) & ((1ull << MAXROWS) - 1ull);
      u64 kkB = (s_nzwB >> ((w - 1) * MAXROWS)) & ((1ull << MAXROWS) - 1ull);
#pragma unroll
      for (int q = 0; q < MAXROWS; ++q) {
        bool hA = (kkA != 0ull);
        int tA = hA ? __builtin_ctzll(kkA) : 0;
        if (hA) kkA &= kkA - 1;
        bqA[q] = hA ? (1ull << ((w - 1) * MAXROWS + tA)) : 0ull;
        LA[q] = 0; HA[q] = 0;
        if (hA) {
          const u64* rp = mb + (size_t)(cA * 64 + (w - 1) * MAXROWS + tA) * WPR;
          if (okLo) LA[q] = rp[l];
          if (okHi) HA[q] = rp[64 + l];
        }
        bool hB = (kkB != 0ull);
        int tB = hB ? __builtin_ctzll(kkB) : 0;
        if (hB) kkB &= kkB - 1;
        bqB[q] = hB ? (1ull << ((w - 1) * MAXROWS + tB)) : 0ull;
        LB[q] = 0; HB[q] = 0;
        if (hB) {
          const u64* rp = mb + (size_t)(cB * 64 + (w - 1) * MAXROWS + tB) * WPR;
          if (okLo) LB[q] = rp[l];
          if (okHi) HB[q] = rp[64 + l];
        }
      }
    }
    __syncthreads();                     // barrier A

    // ---------------- phase 2 (register/LDS only) ----------------
    if (w == 0) {
      u64 a1 = __ballot(nzcA != 0), b1 = __ballot(nzcB != 0);
      if (l == 0) { s_nzwA = a1; s_nzwB = b1; }
    } else {
      u64 kuA = s_kuA, kuB = s_kuB;
#pragma unroll
      for (int q = 0; q < MAXROWS; ++q) {
        if (kuA & bqA[q]) { plo |= LA[q]; phi |= HA[q]; }
        if (kuB & bqB[q]) { plo |= LB[q]; phi |= HB[q]; }
      }
      int wE = cA + 2, wO = cA + 3;
      u64 vE = (wE < 64) ? plo : phi;
      if (l == (wE & 63)) s_slotE[t & 1][w] = vE;
      u64 vO = (wO < 64) ? plo : phi;
      if (l == (wO & 63)) s_slotO[t & 1][w] = vO;
    }
    __syncthreads();                     // barrier B
  }

  // ---------------- fused output ----------------
  const float4* sbx = sboxes + (size_t)b * NB;
  const float* spb = sprob + (size_t)b * NB;
  for (int p = tid; p < NB; p += 512) {
    bool kp = false;
    if (p < K) {
      u64 wv = s_remv[p >> 6];
      kp = !((wv >> (p & 63)) & 1ull);
    }
    float4 bv = sbx[p];
    if (!kp) { bv.x = 0.0f; bv.y = 0.0f; bv.z = 0.0f; bv.w = 0.0f; }
    ((float4*)out)[(size_t)b * NB + p] = bv;
    out[(size_t)BIMG * NB * 4 + (size_t)b * NB + p] = kp ? spb[p] : 0.0f;
    out[(size_t)BIMG * NB * 5 + (size_t)b * NB + p] = kp ? 1.0f : 0.0f;
  }
}

// ---------------------------------------------------------------------------
// Fallback NMS kernel (used only if workspace is too small)
// ---------------------------------------------------------------------------
__global__ __launch_bounds__(1024) void nms_kernel(const float4* __restrict__ sboxes,
                                                   const float* __restrict__ sprob,
                                                   const u32* __restrict__ kcount,
                                                   float* __restrict__ out) {
  __shared__ float4 sb[NB];
  __shared__ unsigned char flag[NB];
  const int b = blockIdx.x;
  const int t = threadIdx.x;
  const int K = (int)kcount[b];

  for (int p = t; p < NB; p += 1024) {
    sb[p] = sboxes[(size_t)b * NB + p];
    flag[p] = (p < K) ? (unsigned char)0 : (unsigned char)1;
  }
  __syncthreads();

  for (int i = 0; i < K; ++i) {
    if (flag[i]) continue;
    float4 bi = sb[i];
    float area_i = (bi.z - bi.x) * (bi.w - bi.y);
    for (int j = i + 1 + t; j < K; j += 1024) {
      float4 bj = sb[j];
      float lx = fmaxf(bi.x, bj.x);
      float ly = fmaxf(bi.y, bj.y);
      float rx = fminf(bi.z, bj.z);
      float ry = fminf(bi.w, bj.w);
      float iw = fmaxf(rx - lx, 0.0f);
      float ih = fmaxf(ry - ly, 0.0f);
      float inter = iw * ih;
      float area_j = (bj.z - bj.x) * (bj.w - bj.y);
      float iou = inter / (area_i + area_j - inter);
      if (iou > 0.5f) flag[j] = (unsigned char)1;
    }
    __syncthreads();
  }

  float4* oboxes = (float4*)(out) + (size_t)b * NB;
  float* oscores = out + (size_t)BIMG * NB * 4 + (size_t)b * NB;
  float* okeep   = out + (size_t)BIMG * NB * 5 + (size_t)b * NB;
  for (int p = t; p < NB; p += 1024) {
    bool kp = (p < K) && (flag[p] == 0);
    float4 bv = sb[p];
    if (!kp) { bv.x = 0.0f; bv.y = 0.0f; bv.z = 0.0f; bv.w = 0.0f; }
    oboxes[p] = bv;
    oscores[p] = kp ? sprob[(size_t)b * NB + p] : 0.0f;
    okeep[p] = kp ? 1.0f : 0.0f;
  }
}

// ---------------------------------------------------------------------------
extern "C" void kernel_launch(void* const* d_in, const int* in_sizes, int n_in,
                              void* d_out, int out_size, void* d_ws, size_t ws_size,
                              hipStream_t stream) {
  const float* offsets = (const float*)d_in[0];   // [B,N,4] f32
  const float* labels  = (const float*)d_in[1];   // [B,N,1] f32
  const float* anchors = (const float*)d_in[2];   // [N,4]   f32
  float* out = (float*)d_out;

  char* ws = (char*)d_ws;
  u32*    kcount = (u32*)(ws + WS_KCOUNT);
  float4* boxes  = (float4*)(ws + WS_BOXES);
  float*  prob   = (float*)(ws + WS_PROB);
  float4* sboxes = (float4*)(ws + WS_SBOXES);
  float*  sprob  = (float*)(ws + WS_SPROB);

  sort_kernel<<<BIMG, 1024, 0, stream>>>(offsets, labels, anchors,
                                         boxes, prob, sboxes, sprob, kcount);

  if (ws_size >= WS_NEEDED) {
    u64*    mask   = (u64*)(ws + WS_MASK);
    unsigned char* rownz = (unsigned char*)(ws + WS_ROWNZ);
    u64*    diag   = (u64*)(ws + WS_DIAG);
    u64*    diag2  = (u64*)(ws + WS_DIAG2);

    mask_kernel<<<dim3(NB / MTILE, BIMG), 512, 0, stream>>>(sboxes, kcount, mask,
                                                            rownz, diag, diag2);

    scan_kernel<<<BIMG, 512, 0, stream>>>(mask, diag, diag2, rownz, kcount,
                                          sboxes, sprob, out);
  } else {
    nms_kernel<<<BIMG, 1024, 0, stream>>>(sboxes, sprob, kcount, out);
  }
}

// Round 15
// 243.359 us; speedup vs baseline: 1.1939x; 1.0078x over previous
//
#include <hip/hip_runtime.h>
#include <cstdint>
#include <cstddef>

typedef unsigned int u32;
typedef unsigned long long u64;

#define NB 8192
#define BIMG 2
#define WPR (NB / 64)   // 128 u64 words per mask row

// ---------------- workspace layout (bytes) ----------------
#define WS_KCOUNT 0
#define WS_KEYS   256                                // (unused, kept for layout)
#define WS_BOXES  (WS_KEYS + BIMG * NB * 8)          // 131328
#define WS_PROB   (WS_BOXES + BIMG * NB * 16)        // 393472
#define WS_SBOXES (WS_PROB + BIMG * NB * 4)          // 459008
#define WS_SPROB  (WS_SBOXES + BIMG * NB * 16)       // 721152
#define WS_REMV   (WS_SPROB + BIMG * NB * 4)         // 786688 (unused in fast path)
#define WS_MASK   (WS_REMV + BIMG * WPR * 8 + 256)   // 788992 (pad)
#define WS_ROWNZ  (WS_MASK + (size_t)BIMG * NB * WPR * 8)
#define WS_DIAG   (WS_ROWNZ + (size_t)BIMG * NB)         // 8-aligned
#define WS_DIAG2  (WS_DIAG + (size_t)BIMG * NB * 8)
#define WS_NEEDED (WS_DIAG2 + (size_t)BIMG * NB * 8)     // ~17.9 MB

__device__ inline u64 rdl64(u64 v, int lane) {
  u32 lo = (u32)__builtin_amdgcn_readlane((int)(u32)v, lane);
  u32 hi = (u32)__builtin_amdgcn_readlane((int)(u32)(v >> 32), lane);
  return ((u64)hi << 32) | lo;
}

__device__ inline u64 shflxor64(u64 v, int off) {
  u32 lo = (u32)v, hi = (u32)(v >> 32);
  lo = (u32)__shfl_xor((int)lo, off, 64);
  hi = (u32)__shfl_xor((int)hi, off, 64);
  return ((u64)hi << 32) | lo;
}

// ---------------------------------------------------------------------------
// Kernel 2 (fused decode + sort + gather): one 1024-thread block per image.
// Hybrid bitonic: register / wave-shfl / LDS phases (r11, verified).
// ---------------------------------------------------------------------------
__global__ __launch_bounds__(1024) void sort_kernel(const float* __restrict__ offsets,
                                                    const float* __restrict__ labels,
                                                    const float* __restrict__ anchors,
                                                    float4* __restrict__ boxes,
                                                    float* __restrict__ prob,
                                                    float4* __restrict__ sboxes,
                                                    float* __restrict__ sprob,
                                                    u32* __restrict__ kcount) {
  __shared__ u64 s[NB];                 // 64 KB
  __shared__ u32 scnt;
  const int b = blockIdx.x;
  const int tid = threadIdx.x;
  if (tid == 0) scnt = 0;

  // ---- fused decode (coalesced): element n = q*1024 + tid ----
  u32 lc = 0;
  for (int q = 0; q < 8; ++q) {
    int n = (q << 10) + tid;
    int idx = b * NB + n;
    float logit = labels[idx];
    float p = 1.0f / (1.0f + expf(-logit));
    bool valid = p > 0.5f;

    const float4 an = ((const float4*)anchors)[n];   // x1,y1,x2,y2
    float acx = (an.x + an.z) / 2.0f;
    float acy = (an.y + an.w) / 2.0f;
    float aw = an.z - an.x;
    float ah = an.w - an.y;

    const float4 of = ((const float4*)offsets)[idx]; // gcx,gcy,gw,gh
    float cx = of.x * aw / 10.0f + acx;
    float cy = of.y * ah / 10.0f + acy;
    float w = expf(of.z / 5.0f) * aw;
    float h = expf(of.w / 5.0f) * ah;

    float4 bx;
    bx.x = cx - w / 2.0f;
    bx.y = cy - h / 2.0f;
    bx.z = cx + w / 2.0f;
    bx.w = cy + h / 2.0f;
    boxes[idx] = bx;
    prob[idx] = p;

    u32 e32 = valid ? (__float_as_uint(p) ^ 0x80000000u) : 0u;
    s[n] = ((u64)e32 << 32) | (u32)(~(u32)n);
    lc += valid ? 1u : 0u;
  }
  for (int off = 32; off > 0; off >>= 1) lc += __shfl_down(lc, off, 64);
  __syncthreads();
  if ((tid & 63) == 0) atomicAdd(&scnt, lc);
  __syncthreads();
  if (tid == 0) kcount[b] = scnt;

  u64 e[8];
#pragma unroll
  for (int r = 0; r < 8; ++r) e[r] = s[tid * 8 + r];

  for (int k = 2; k <= NB; k <<= 1) {
    int j = k >> 1;
    if (j >= 512) {
#pragma unroll
      for (int r = 0; r < 8; ++r) s[tid * 8 + r] = e[r];
      __syncthreads();
      for (; j >= 512; j >>= 1) {
        for (int p = tid; p < NB / 2; p += 1024) {
          int i = ((p & ~(j - 1)) << 1) | (p & (j - 1));
          int ixj = i | j;
          u64 a = s[i];
          u64 c = s[ixj];
          bool desc = (i & k) == 0;
          if ((a < c) == desc) { s[i] = c; s[ixj] = a; }
        }
        __syncthreads();
      }
#pragma unroll
      for (int r = 0; r < 8; ++r) e[r] = s[tid * 8 + r];
    }
    for (; j >= 8; j >>= 1) {
      int m = j >> 3;
      bool lowSide = (tid & m) == 0;
      bool descT = ((tid * 8) & k) == 0;
      bool takeMax = (lowSide == descT);
#pragma unroll
      for (int r = 0; r < 8; ++r) {
        u64 p = shflxor64(e[r], m);
        bool sel = (e[r] < p) == takeMax;
        e[r] = sel ? p : e[r];
      }
    }
    for (; j >= 1; j >>= 1) {
#pragma unroll
      for (int r = 0; r < 8; ++r) {
        if ((r & j) == 0) {
          int i = tid * 8 + r;
          bool desc = (i & k) == 0;
          u64 a = e[r];
          u64 c = e[r | j];
          if ((a < c) == desc) { e[r] = c; e[r | j] = a; }
        }
      }
    }
  }

#pragma unroll
  for (int r = 0; r < 8; ++r) s[tid * 8 + r] = e[r];
  __syncthreads();
  for (int q = 0; q < 8; ++q) {
    int i = (q << 10) + tid;
    u64 kk = s[i];
    u32 oi = (u32)(~kk);
    sboxes[(size_t)b * NB + i] = boxes[(size_t)b * NB + oi];
    sprob[(size_t)b * NB + i]  = prob[(size_t)b * NB + oi];
  }
}

// ---------------------------------------------------------------------------
// Kernel 4: overlap bitmask build — TILED, lane-per-row, NO cross-lane ops.
// Block = 64 consecutive sorted rows; 512 thr (8 waves). Lane r holds row
// i0+r's box in registers. Wave wv handles words w = tc+wv, tc+wv+8, ...:
// stages the word's 64 bj into its private LDS buffer (coalesced load, no
// barrier needed — per-wave buffer), then each lane builds its own 64-bit
// word with independent per-lane IoUs: word |= pred << jj. Zero ballots.
// Write-set / predicate / IoU expression identical to the proven r11 mask.
// ---------------------------------------------------------------------------
#define MTILE 64

__global__ __launch_bounds__(512) void mask_kernel(const float4* __restrict__ sboxes,
                                                   const u32* __restrict__ kcount,
                                                   u64* __restrict__ mask,
                                                   unsigned char* __restrict__ rownz,
                                                   u64* __restrict__ diag,
                                                   u64* __restrict__ diag2) {
  const int b = blockIdx.y;
  const int K = (int)kcount[b];
  const int i0 = blockIdx.x * MTILE;
  if (i0 >= K) return;
  const int wv = threadIdx.x >> 6;     // wave 0..7
  const int lane = threadIdx.x & 63;
  const int tc = i0 >> 6;
  const int NC = min(WPR, (K + 63) >> 6);
  __shared__ float4 s_bj[8][MTILE];    // per-wave bj buffer (8 KB)
  __shared__ u32 s_any[MTILE];
  if (threadIdx.x < MTILE) s_any[threadIdx.x] = 0;
  __syncthreads();                     // s_any init before any atomicOr

  const int irow = i0 + lane;          // this lane's row (always < NB)
  const float4 bi = sboxes[(size_t)b * NB + irow];
  const float area_i = (bi.z - bi.x) * (bi.w - bi.y);
  const bool rowok = (irow < K);
  u64* mrow = mask + ((size_t)b * NB + irow) * WPR;
  u32 anyacc = 0;

  for (int w = tc + wv; w < NC; w += 8) {
    // stage this word's 64 bj (coalesced; wave-private buffer, no barrier)
    s_bj[wv][lane] = sboxes[(size_t)b * NB + w * 64 + lane];
    const int jbase = w * 64;
    const bool wdiag = (w == tc);      // diagonal word: need jj > lane
    u64 word = 0;
#pragma unroll 8
    for (int jj = 0; jj < 64; ++jj) {
      float4 bj = s_bj[wv][jj];
      float lx = fmaxf(bi.x, bj.x);
      float ly = fmaxf(bi.y, bj.y);
      float rx = fminf(bi.z, bj.z);
      float ry = fminf(bi.w, bj.w);
      float iw = fmaxf(rx - lx, 0.0f);
      float ih = fmaxf(ry - ly, 0.0f);
      float inter = iw * ih;
      float area_j = (bj.z - bj.x) * (bj.w - bj.y);
      float iou = inter / (area_i + area_j - inter);
      bool pred = (!wdiag || (jj > lane)) && (jbase + jj < K) && (iou > 0.5f);
      word |= pred ? (1ull << jj) : 0ull;
    }
    if (rowok) {
      mrow[w] = word;
      if (w == tc)          diag[(size_t)b * NB + irow]  = word;
      else if (w == tc + 1) diag2[(size_t)b * NB + irow] = word;
      anyacc |= (word != 0ull) ? 1u : 0u;
    }
  }
  if (anyacc) atomicOr(&s_any[lane], 1u);
  __syncthreads();
  if (threadIdx.x < MTILE) {
    int i = i0 + threadIdx.x;
    if (i < K) rownz[(size_t)b * NB + i] = (unsigned char)(s_any[threadIdx.x] ? 1 : 0);
  }
}

// ---------------------------------------------------------------------------
// Kernel 5: PAIRED chunked greedy scan + fused output (r10/r11, verified 92us).
// ---------------------------------------------------------------------------
#define SCAN_WAVES 8
#define MAXROWS 10

__device__ inline void resolve_diag(u64& rc, u64 dw) {
  u64 nzd = __ballot(dw != 0ull) & ~rc;
  while (nzd) {
    int tt = __builtin_ctzll(nzd);
    rc |= rdl64(dw, tt);
    nzd &= ~(1ull << tt) & ~rc;
  }
}

__global__ __launch_bounds__(512) void scan_kernel(const u64* __restrict__ mask,
                                                   const u64* __restrict__ diag,
                                                   const u64* __restrict__ diag2,
                                                   const unsigned char* __restrict__ rownz,
                                                   const u32* __restrict__ kcount,
                                                   const float4* __restrict__ sboxes,
                                                   const float* __restrict__ sprob,
                                                   float* __restrict__ out) {
  __shared__ u64 s_remv[WPR];               // finalized rc words (1 KB)
  __shared__ u64 s_slotE[2][SCAN_WAVES];    // posts of word 2t+2
  __shared__ u64 s_slotO[2][SCAN_WAVES];    // posts of word 2t+3
  __shared__ u64 s_kuA, s_kuB, s_nzwA, s_nzwB;
  const int b = blockIdx.x;
  const int tid = threadIdx.x;
  const int w = tid >> 6;                   // wave id 0..7
  const int l = tid & 63;
  const int K = (int)kcount[b];
  const u64* mb = mask + (size_t)b * NB * WPR;
  const u64* dg = diag + (size_t)b * NB;
  const u64* dg2 = diag2 + (size_t)b * NB;
  const unsigned char* nzb = rownz + (size_t)b * NB;
  const int NC = min(WPR, (K + 63) >> 6);
  const int NCL = min(NC, 64);
  const int NP = (NC + 1) >> 1;             // chunk pairs

  if (tid < 2 * SCAN_WAVES) { ((u64*)s_slotE)[tid] = 0; ((u64*)s_slotO)[tid] = 0; }

  u64 plo = 0, phi = 0;
  const bool okLo = (l < NCL);
  const bool okHi = (64 + l) < NC;
  u64 LA[MAXROWS], HA[MAXROWS], LB[MAXROWS], HB[MAXROWS];
  u64 bqA[MAXROWS], bqB[MAXROWS];
  u64 dwA = 0, dwB = 0, cw = 0;
  unsigned char nzcA = 0, nzcB = 0;

  if (w == 0 && NP > 0) {
    int rA = l, rB = 64 + l;
    dwA = (rA < K) ? dg[rA] : 0ull;
    dwB = (rB < K) ? dg[rB] : 0ull;
    cw  = (rA < K) ? dg2[rA] : 0ull;
    nzcA = (rA < K) ? nzb[rA] : (unsigned char)0;
    nzcB = (rB < K) ? nzb[rB] : (unsigned char)0;
    u64 a0 = __ballot(nzcA != 0), b0 = __ballot(nzcB != 0);
    if (l == 0) { s_nzwA = a0; s_nzwB = b0; }
  }
  __syncthreads();

  for (int t = 0; t < NP; ++t) {
    const int cA = 2 * t, cB = 2 * t + 1;
    const bool hasB = (cB < NC);
    // ---------------- phase 1 ----------------
    if (w == 0) {
      u64 dwA_n = 0, dwB_n = 0, cw_n = 0;
      unsigned char nzA_n = 0, nzB_n = 0;
      if (t + 1 < NP) {
        int rA = (t + 1) * 128 + l, rB = (t + 1) * 128 + 64 + l;
        dwA_n = (rA < K) ? dg[rA] : 0ull;
        dwB_n = (rB < K) ? dg[rB] : 0ull;
        cw_n  = (rA < K) ? dg2[rA] : 0ull;
        nzA_n = (rA < K) ? nzb[rA] : (unsigned char)0;
        nzB_n = (rB < K) ? nzb[rB] : (unsigned char)0;
      }
      int pr = (t + 1) & 1;
      u64 valA = s_slotE[pr][l & (SCAN_WAVES - 1)];
      u64 valB = s_slotO[pr][l & (SCAN_WAVES - 1)];
#pragma unroll
      for (int off = 1; off < SCAN_WAVES; off <<= 1) {
        valA |= shflxor64(valA, off);
        valB |= shflxor64(valB, off);
      }
      int loA = cA * 64;
      u64 tailA = (loA + 64 <= K) ? 0ull : ((~0ull) << (K - loA));
      u64 rcA = valA | tailA;
      u64 nzwA = __ballot(nzcA != 0);
      resolve_diag(rcA, dwA);
      u64 kuA = (~rcA) & nzwA;
      u64 m = ((~rcA >> l) & 1ull) ? cw : 0ull;
#pragma unroll
      for (int off = 32; off > 0; off >>= 1) m |= shflxor64(m, off);
      u64 rcB = ~0ull, kuB = 0;
      if (hasB) {
        int loB = cB * 64;
        u64 tailB = (loB + 64 <= K) ? 0ull : ((~0ull) << (K - loB));
        rcB = valB | tailB | m;
        u64 nzwB = __ballot(nzcB != 0);
        resolve_diag(rcB, dwB);
        kuB = (~rcB) & nzwB;
      }
      if (l == 0) {
        s_remv[cA] = rcA;
        if (hasB) s_remv[cB] = rcB;
        s_kuA = kuA; s_kuB = kuB;
      }
      dwA = dwA_n; dwB = dwB_n; cw = cw_n; nzcA = nzA_n; nzcB = nzB_n;
    } else {
      u64 kkA = (s_nzwA >> ((w - 1) * MAXROWS)) & ((1ull << MAXROWS) - 1ull);
      u64 kkB = (s_nzwB >> ((w - 1) * MAXROWS)) & ((1ull << MAXROWS) - 1ull);
#pragma unroll
      for (int q = 0; q < MAXROWS; ++q) {
        bool hA = (kkA != 0ull);
        int tA = hA ? __builtin_ctzll(kkA) : 0;
        if (hA) kkA &= kkA - 1;
        bqA[q] = hA ? (1ull << ((w - 1) * MAXROWS + tA)) : 0ull;
        LA[q] = 0; HA[q] = 0;
        if (hA) {
          const u64* rp = mb + (size_t)(cA * 64 + (w - 1) * MAXROWS + tA) * WPR;
          if (okLo) LA[q] = rp[l];
          if (okHi) HA[q] = rp[64 + l];
        }
        bool hB = (kkB != 0ull);
        int tB = hB ? __builtin_ctzll(kkB) : 0;
        if (hB) kkB &= kkB - 1;
        bqB[q] = hB ? (1ull << ((w - 1) * MAXROWS + tB)) : 0ull;
        LB[q] = 0; HB[q] = 0;
        if (hB) {
          const u64* rp = mb + (size_t)(cB * 64 + (w - 1) * MAXROWS + tB) * WPR;
          if (okLo) LB[q] = rp[l];
          if (okHi) HB[q] = rp[64 + l];
        }
      }
    }
    __syncthreads();                     // barrier A

    // ---------------- phase 2 (register/LDS only) ----------------
    if (w == 0) {
      u64 a1 = __ballot(nzcA != 0), b1 = __ballot(nzcB != 0);
      if (l == 0) { s_nzwA = a1; s_nzwB = b1; }
    } else {
      u64 kuA = s_kuA, kuB = s_kuB;
#pragma unroll
      for (int q = 0; q < MAXROWS; ++q) {
        if (kuA & bqA[q]) { plo |= LA[q]; phi |= HA[q]; }
        if (kuB & bqB[q]) { plo |= LB[q]; phi |= HB[q]; }
      }
      int wE = cA + 2, wO = cA + 3;
      u64 vE = (wE < 64) ? plo : phi;
      if (l == (wE & 63)) s_slotE[t & 1][w] = vE;
      u64 vO = (wO < 64) ? plo : phi;
      if (l == (wO & 63)) s_slotO[t & 1][w] = vO;
    }
    __syncthreads();                     // barrier B
  }

  // ---------------- fused output ----------------
  const float4* sbx = sboxes + (size_t)b * NB;
  const float* spb = sprob + (size_t)b * NB;
  for (int p = tid; p < NB; p += 512) {
    bool kp = false;
    if (p < K) {
      u64 wv = s_remv[p >> 6];
      kp = !((wv >> (p & 63)) & 1ull);
    }
    float4 bv = sbx[p];
    if (!kp) { bv.x = 0.0f; bv.y = 0.0f; bv.z = 0.0f; bv.w = 0.0f; }
    ((float4*)out)[(size_t)b * NB + p] = bv;
    out[(size_t)BIMG * NB * 4 + (size_t)b * NB + p] = kp ? spb[p] : 0.0f;
    out[(size_t)BIMG * NB * 5 + (size_t)b * NB + p] = kp ? 1.0f : 0.0f;
  }
}

// ---------------------------------------------------------------------------
// Fallback NMS kernel (used only if workspace is too small)
// ---------------------------------------------------------------------------
__global__ __launch_bounds__(1024) void nms_kernel(const float4* __restrict__ sboxes,
                                                   const float* __restrict__ sprob,
                                                   const u32* __restrict__ kcount,
                                                   float* __restrict__ out) {
  __shared__ float4 sb[NB];
  __shared__ unsigned char flag[NB];
  const int b = blockIdx.x;
  const int t = threadIdx.x;
  const int K = (int)kcount[b];

  for (int p = t; p < NB; p += 1024) {
    sb[p] = sboxes[(size_t)b * NB + p];
    flag[p] = (p < K) ? (unsigned char)0 : (unsigned char)1;
  }
  __syncthreads();

  for (int i = 0; i < K; ++i) {
    if (flag[i]) continue;
    float4 bi = sb[i];
    float area_i = (bi.z - bi.x) * (bi.w - bi.y);
    for (int j = i + 1 + t; j < K; j += 1024) {
      float4 bj = sb[j];
      float lx = fmaxf(bi.x, bj.x);
      float ly = fmaxf(bi.y, bj.y);
      float rx = fminf(bi.z, bj.z);
      float ry = fminf(bi.w, bj.w);
      float iw = fmaxf(rx - lx, 0.0f);
      float ih = fmaxf(ry - ly, 0.0f);
      float inter = iw * ih;
      float area_j = (bj.z - bj.x) * (bj.w - bj.y);
      float iou = inter / (area_i + area_j - inter);
      if (iou > 0.5f) flag[j] = (unsigned char)1;
    }
    __syncthreads();
  }

  float4* oboxes = (float4*)(out) + (size_t)b * NB;
  float* oscores = out + (size_t)BIMG * NB * 4 + (size_t)b * NB;
  float* okeep   = out + (size_t)BIMG * NB * 5 + (size_t)b * NB;
  for (int p = t; p < NB; p += 1024) {
    bool kp = (p < K) && (flag[p] == 0);
    float4 bv = sb[p];
    if (!kp) { bv.x = 0.0f; bv.y = 0.0f; bv.z = 0.0f; bv.w = 0.0f; }
    oboxes[p] = bv;
    oscores[p] = kp ? sprob[(size_t)b * NB + p] : 0.0f;
    okeep[p] = kp ? 1.0f : 0.0f;
  }
}

// ---------------------------------------------------------------------------
extern "C" void kernel_launch(void* const* d_in, const int* in_sizes, int n_in,
                              void* d_out, int out_size, void* d_ws, size_t ws_size,
                              hipStream_t stream) {
  const float* offsets = (const float*)d_in[0];   // [B,N,4] f32
  const float* labels  = (const float*)d_in[1];   // [B,N,1] f32
  const float* anchors = (const float*)d_in[2];   // [N,4]   f32
  float* out = (float*)d_out;

  char* ws = (char*)d_ws;
  u32*    kcount = (u32*)(ws + WS_KCOUNT);
  float4* boxes  = (float4*)(ws + WS_BOXES);
  float*  prob   = (float*)(ws + WS_PROB);
  float4* sboxes = (float4*)(ws + WS_SBOXES);
  float*  sprob  = (float*)(ws + WS_SPROB);

  sort_kernel<<<BIMG, 1024, 0, stream>>>(offsets, labels, anchors,
                                         boxes, prob, sboxes, sprob, kcount);

  if (ws_size >= WS_NEEDED) {
    u64*    mask   = (u64*)(ws + WS_MASK);
    unsigned char* rownz = (unsigned char*)(ws + WS_ROWNZ);
    u64*    diag   = (u64*)(ws + WS_DIAG);
    u64*    diag2  = (u64*)(ws + WS_DIAG2);

    mask_kernel<<<dim3(NB / MTILE, BIMG), 512, 0, stream>>>(sboxes, kcount, mask,
                                                            rownz, diag, diag2);

    scan_kernel<<<BIMG, 512, 0, stream>>>(mask, diag, diag2, rownz, kcount,
                                          sboxes, sprob, out);
  } else {
    nms_kernel<<<BIMG, 1024, 0, stream>>>(sboxes, sprob, kcount, out);
  }
}

// Round 16
// 207.595 us; speedup vs baseline: 1.3995x; 1.1723x over previous
//
#include <hip/hip_runtime.h>
#include <cstdint>
#include <cstddef>

typedef unsigned int u32;
typedef unsigned long long u64;

#define NB 8192
#define BIMG 2
#define WPR (NB / 64)   // 128 u64 words per mask row

// ---------------- workspace layout (bytes) ----------------
#define WS_KCOUNT 0
#define WS_KEYS   256                                // (unused, kept for layout)
#define WS_BOXES  (WS_KEYS + BIMG * NB * 8)          // 131328
#define WS_PROB   (WS_BOXES + BIMG * NB * 16)        // 393472
#define WS_SBOXES (WS_PROB + BIMG * NB * 4)          // 459008
#define WS_SPROB  (WS_SBOXES + BIMG * NB * 16)       // 721152
#define WS_REMV   (WS_SPROB + BIMG * NB * 4)         // 786688 (unused in fast path)
#define WS_MASK   (WS_REMV + BIMG * WPR * 8 + 256)   // 788992 (pad)
#define WS_ROWNZ  (WS_MASK + (size_t)BIMG * NB * WPR * 8)
#define WS_DIAG   (WS_ROWNZ + (size_t)BIMG * NB)         // 8-aligned
#define WS_DIAG2  (WS_DIAG + (size_t)BIMG * NB * 8)
#define WS_NEEDED (WS_DIAG2 + (size_t)BIMG * NB * 8)     // ~17.9 MB

__device__ inline u64 rdl64(u64 v, int lane) {
  u32 lo = (u32)__builtin_amdgcn_readlane((int)(u32)v, lane);
  u32 hi = (u32)__builtin_amdgcn_readlane((int)(u32)(v >> 32), lane);
  return ((u64)hi << 32) | lo;
}

__device__ inline u64 shflxor64(u64 v, int off) {
  u32 lo = (u32)v, hi = (u32)(v >> 32);
  lo = (u32)__shfl_xor((int)lo, off, 64);
  hi = (u32)__shfl_xor((int)hi, off, 64);
  return ((u64)hi << 32) | lo;
}

// ---------------------------------------------------------------------------
// Kernel 2 (fused decode + sort + gather): one 1024-thread block per image.
// Hybrid bitonic: register / wave-shfl / LDS phases (r11, verified 216us).
// ---------------------------------------------------------------------------
__global__ __launch_bounds__(1024) void sort_kernel(const float* __restrict__ offsets,
                                                    const float* __restrict__ labels,
                                                    const float* __restrict__ anchors,
                                                    float4* __restrict__ boxes,
                                                    float* __restrict__ prob,
                                                    float4* __restrict__ sboxes,
                                                    float* __restrict__ sprob,
                                                    u32* __restrict__ kcount) {
  __shared__ u64 s[NB];                 // 64 KB
  __shared__ u32 scnt;
  const int b = blockIdx.x;
  const int tid = threadIdx.x;
  if (tid == 0) scnt = 0;

  // ---- fused decode (coalesced): element n = q*1024 + tid ----
  u32 lc = 0;
  for (int q = 0; q < 8; ++q) {
    int n = (q << 10) + tid;
    int idx = b * NB + n;
    float logit = labels[idx];
    float p = 1.0f / (1.0f + expf(-logit));
    bool valid = p > 0.5f;

    const float4 an = ((const float4*)anchors)[n];   // x1,y1,x2,y2
    float acx = (an.x + an.z) / 2.0f;
    float acy = (an.y + an.w) / 2.0f;
    float aw = an.z - an.x;
    float ah = an.w - an.y;

    const float4 of = ((const float4*)offsets)[idx]; // gcx,gcy,gw,gh
    float cx = of.x * aw / 10.0f + acx;
    float cy = of.y * ah / 10.0f + acy;
    float w = expf(of.z / 5.0f) * aw;
    float h = expf(of.w / 5.0f) * ah;

    float4 bx;
    bx.x = cx - w / 2.0f;
    bx.y = cy - h / 2.0f;
    bx.z = cx + w / 2.0f;
    bx.w = cy + h / 2.0f;
    boxes[idx] = bx;
    prob[idx] = p;

    u32 e32 = valid ? (__float_as_uint(p) ^ 0x80000000u) : 0u;
    s[n] = ((u64)e32 << 32) | (u32)(~(u32)n);
    lc += valid ? 1u : 0u;
  }
  for (int off = 32; off > 0; off >>= 1) lc += __shfl_down(lc, off, 64);
  __syncthreads();
  if ((tid & 63) == 0) atomicAdd(&scnt, lc);
  __syncthreads();
  if (tid == 0) kcount[b] = scnt;

  u64 e[8];
#pragma unroll
  for (int r = 0; r < 8; ++r) e[r] = s[tid * 8 + r];

  for (int k = 2; k <= NB; k <<= 1) {
    int j = k >> 1;
    if (j >= 512) {
#pragma unroll
      for (int r = 0; r < 8; ++r) s[tid * 8 + r] = e[r];
      __syncthreads();
      for (; j >= 512; j >>= 1) {
        for (int p = tid; p < NB / 2; p += 1024) {
          int i = ((p & ~(j - 1)) << 1) | (p & (j - 1));
          int ixj = i | j;
          u64 a = s[i];
          u64 c = s[ixj];
          bool desc = (i & k) == 0;
          if ((a < c) == desc) { s[i] = c; s[ixj] = a; }
        }
        __syncthreads();
      }
#pragma unroll
      for (int r = 0; r < 8; ++r) e[r] = s[tid * 8 + r];
    }
    for (; j >= 8; j >>= 1) {
      int m = j >> 3;
      bool lowSide = (tid & m) == 0;
      bool descT = ((tid * 8) & k) == 0;
      bool takeMax = (lowSide == descT);
#pragma unroll
      for (int r = 0; r < 8; ++r) {
        u64 p = shflxor64(e[r], m);
        bool sel = (e[r] < p) == takeMax;
        e[r] = sel ? p : e[r];
      }
    }
    for (; j >= 1; j >>= 1) {
#pragma unroll
      for (int r = 0; r < 8; ++r) {
        if ((r & j) == 0) {
          int i = tid * 8 + r;
          bool desc = (i & k) == 0;
          u64 a = e[r];
          u64 c = e[r | j];
          if ((a < c) == desc) { e[r] = c; e[r | j] = a; }
        }
      }
    }
  }

#pragma unroll
  for (int r = 0; r < 8; ++r) s[tid * 8 + r] = e[r];
  __syncthreads();
  for (int q = 0; q < 8; ++q) {
    int i = (q << 10) + tid;
    u64 kk = s[i];
    u32 oi = (u32)(~kk);
    sboxes[(size_t)b * NB + i] = boxes[(size_t)b * NB + oi];
    sprob[(size_t)b * NB + i]  = prob[(size_t)b * NB + oi];
  }
}

// ---------------------------------------------------------------------------
// Kernel 4: overlap bitmask build (r11 naive form — best measured). One block
// per (sorted row, image). Only change vs r11: pass loop starts at tc>>2
// (skipped passes have act==false for every wave -> identical write-set).
// ---------------------------------------------------------------------------
__global__ __launch_bounds__(256) void mask_kernel(const float4* __restrict__ sboxes,
                                                   const u32* __restrict__ kcount,
                                                   u64* __restrict__ mask,
                                                   unsigned char* __restrict__ rownz,
                                                   u64* __restrict__ diag,
                                                   u64* __restrict__ diag2) {
  const int i = blockIdx.x;       // sorted row
  const int b = blockIdx.y;
  const int K = (int)kcount[b];
  if (i >= K) return;
  const int wave = threadIdx.x >> 6;
  const int lane = threadIdx.x & 63;
  const int tc = i >> 6;
  __shared__ u32 anyf[4];
  const float4* sb = sboxes + (size_t)b * NB;
  const float4 bi = sb[i];
  const float area_i = (bi.z - bi.x) * (bi.w - bi.y);
  u64* mrow = mask + ((size_t)b * NB + i) * WPR;
  bool any = false;
  for (int pass = tc >> 2; pass < WPR / 4; ++pass) {
    int w = pass * 4 + wave;
    u64 word = 0;
    bool act = ((w + 1) * 64 > i) && (w * 64 < K);   // uniform per wave
    if (act) {
      int j = w * 64 + lane;
      float4 bj = sb[j];
      float lx = fmaxf(bi.x, bj.x);
      float ly = fmaxf(bi.y, bj.y);
      float rx = fminf(bi.z, bj.z);
      float ry = fminf(bi.w, bj.w);
      float iw = fmaxf(rx - lx, 0.0f);
      float ih = fmaxf(ry - ly, 0.0f);
      float inter = iw * ih;
      float area_j = (bj.z - bj.x) * (bj.w - bj.y);
      float iou = inter / (area_i + area_j - inter);
      bool pred = (j > i) && (j < K) && (iou > 0.5f);
      word = __ballot(pred);
      any = any || (word != 0ull);
    }
    if (lane == 0) {
      if (act) mrow[w] = word;
      if (w == tc)          diag[(size_t)b * NB + i]  = word;
      else if (w == tc + 1) diag2[(size_t)b * NB + i] = word;   // 0 if !act
    }
  }
  if (lane == 0) anyf[wave] = any ? 1u : 0u;
  __syncthreads();
  if (threadIdx.x == 0) {
    u32 a = anyf[0] | anyf[1] | anyf[2] | anyf[3];
    rownz[(size_t)b * NB + i] = (unsigned char)(a ? 1 : 0);
  }
}

// ---------------------------------------------------------------------------
// Kernel 5: PAIRED chunked greedy scan + fused output (r10/r11, verified 92us).
// ---------------------------------------------------------------------------
#define SCAN_WAVES 8
#define MAXROWS 10

__device__ inline void resolve_diag(u64& rc, u64 dw) {
  u64 nzd = __ballot(dw != 0ull) & ~rc;
  while (nzd) {
    int tt = __builtin_ctzll(nzd);
    rc |= rdl64(dw, tt);
    nzd &= ~(1ull << tt) & ~rc;
  }
}

__global__ __launch_bounds__(512) void scan_kernel(const u64* __restrict__ mask,
                                                   const u64* __restrict__ diag,
                                                   const u64* __restrict__ diag2,
                                                   const unsigned char* __restrict__ rownz,
                                                   const u32* __restrict__ kcount,
                                                   const float4* __restrict__ sboxes,
                                                   const float* __restrict__ sprob,
                                                   float* __restrict__ out) {
  __shared__ u64 s_remv[WPR];               // finalized rc words (1 KB)
  __shared__ u64 s_slotE[2][SCAN_WAVES];    // posts of word 2t+2
  __shared__ u64 s_slotO[2][SCAN_WAVES];    // posts of word 2t+3
  __shared__ u64 s_kuA, s_kuB, s_nzwA, s_nzwB;
  const int b = blockIdx.x;
  const int tid = threadIdx.x;
  const int w = tid >> 6;                   // wave id 0..7
  const int l = tid & 63;
  const int K = (int)kcount[b];
  const u64* mb = mask + (size_t)b * NB * WPR;
  const u64* dg = diag + (size_t)b * NB;
  const u64* dg2 = diag2 + (size_t)b * NB;
  const unsigned char* nzb = rownz + (size_t)b * NB;
  const int NC = min(WPR, (K + 63) >> 6);
  const int NCL = min(NC, 64);
  const int NP = (NC + 1) >> 1;             // chunk pairs

  if (tid < 2 * SCAN_WAVES) { ((u64*)s_slotE)[tid] = 0; ((u64*)s_slotO)[tid] = 0; }

  u64 plo = 0, phi = 0;
  const bool okLo = (l < NCL);
  const bool okHi = (64 + l) < NC;
  u64 LA[MAXROWS], HA[MAXROWS], LB[MAXROWS], HB[MAXROWS];
  u64 bqA[MAXROWS], bqB[MAXROWS];
  u64 dwA = 0, dwB = 0, cw = 0;
  unsigned char nzcA = 0, nzcB = 0;

  if (w == 0 && NP > 0) {
    int rA = l, rB = 64 + l;
    dwA = (rA < K) ? dg[rA] : 0ull;
    dwB = (rB < K) ? dg[rB] : 0ull;
    cw  = (rA < K) ? dg2[rA] : 0ull;
    nzcA = (rA < K) ? nzb[rA] : (unsigned char)0;
    nzcB = (rB < K) ? nzb[rB] : (unsigned char)0;
    u64 a0 = __ballot(nzcA != 0), b0 = __ballot(nzcB != 0);
    if (l == 0) { s_nzwA = a0; s_nzwB = b0; }
  }
  __syncthreads();

  for (int t = 0; t < NP; ++t) {
    const int cA = 2 * t, cB = 2 * t + 1;
    const bool hasB = (cB < NC);
    // ---------------- phase 1 ----------------
    if (w == 0) {
      u64 dwA_n = 0, dwB_n = 0, cw_n = 0;
      unsigned char nzA_n = 0, nzB_n = 0;
      if (t + 1 < NP) {
        int rA = (t + 1) * 128 + l, rB = (t + 1) * 128 + 64 + l;
        dwA_n = (rA < K) ? dg[rA] : 0ull;
        dwB_n = (rB < K) ? dg[rB] : 0ull;
        cw_n  = (rA < K) ? dg2[rA] : 0ull;
        nzA_n = (rA < K) ? nzb[rA] : (unsigned char)0;
        nzB_n = (rB < K) ? nzb[rB] : (unsigned char)0;
      }
      int pr = (t + 1) & 1;
      u64 valA = s_slotE[pr][l & (SCAN_WAVES - 1)];
      u64 valB = s_slotO[pr][l & (SCAN_WAVES - 1)];
#pragma unroll
      for (int off = 1; off < SCAN_WAVES; off <<= 1) {
        valA |= shflxor64(valA, off);
        valB |= shflxor64(valB, off);
      }
      int loA = cA * 64;
      u64 tailA = (loA + 64 <= K) ? 0ull : ((~0ull) << (K - loA));
      u64 rcA = valA | tailA;
      u64 nzwA = __ballot(nzcA != 0);
      resolve_diag(rcA, dwA);
      u64 kuA = (~rcA) & nzwA;
      u64 m = ((~rcA >> l) & 1ull) ? cw : 0ull;
#pragma unroll
      for (int off = 32; off > 0; off >>= 1) m |= shflxor64(m, off);
      u64 rcB = ~0ull, kuB = 0;
      if (hasB) {
        int loB = cB * 64;
        u64 tailB = (loB + 64 <= K) ? 0ull : ((~0ull) << (K - loB));
        rcB = valB | tailB | m;
        u64 nzwB = __ballot(nzcB != 0);
        resolve_diag(rcB, dwB);
        kuB = (~rcB) & nzwB;
      }
      if (l == 0) {
        s_remv[cA] = rcA;
        if (hasB) s_remv[cB] = rcB;
        s_kuA = kuA; s_kuB = kuB;
      }
      dwA = dwA_n; dwB = dwB_n; cw = cw_n; nzcA = nzA_n; nzcB = nzB_n;
    } else {
      u64 kkA = (s_nzwA >> ((w - 1) * MAXROWS)) & ((1ull << MAXROWS) - 1ull);
      u64 kkB = (s_nzwB >> ((w - 1) * MAXROWS)) & ((1ull << MAXROWS) - 1ull);
#pragma unroll
      for (int q = 0; q < MAXROWS; ++q) {
        bool hA = (kkA != 0ull);
        int tA = hA ? __builtin_ctzll(kkA) : 0;
        if (hA) kkA &= kkA - 1;
        bqA[q] = hA ? (1ull << ((w - 1) * MAXROWS + tA)) : 0ull;
        LA[q] = 0; HA[q] = 0;
        if (hA) {
          const u64* rp = mb + (size_t)(cA * 64 + (w - 1) * MAXROWS + tA) * WPR;
          if (okLo) LA[q] = rp[l];
          if (okHi) HA[q] = rp[64 + l];
        }
        bool hB = (kkB != 0ull);
        int tB = hB ? __builtin_ctzll(kkB) : 0;
        if (hB) kkB &= kkB - 1;
        bqB[q] = hB ? (1ull << ((w - 1) * MAXROWS + tB)) : 0ull;
        LB[q] = 0; HB[q] = 0;
        if (hB) {
          const u64* rp = mb + (size_t)(cB * 64 + (w - 1) * MAXROWS + tB) * WPR;
          if (okLo) LB[q] = rp[l];
          if (okHi) HB[q] = rp[64 + l];
        }
      }
    }
    __syncthreads();                     // barrier A

    // ---------------- phase 2 (register/LDS only) ----------------
    if (w == 0) {
      u64 a1 = __ballot(nzcA != 0), b1 = __ballot(nzcB != 0);
      if (l == 0) { s_nzwA = a1; s_nzwB = b1; }
    } else {
      u64 kuA = s_kuA, kuB = s_kuB;
#pragma unroll
      for (int q = 0; q < MAXROWS; ++q) {
        if (kuA & bqA[q]) { plo |= LA[q]; phi |= HA[q]; }
        if (kuB & bqB[q]) { plo |= LB[q]; phi |= HB[q]; }
      }
      int wE = cA + 2, wO = cA + 3;
      u64 vE = (wE < 64) ? plo : phi;
      if (l == (wE & 63)) s_slotE[t & 1][w] = vE;
      u64 vO = (wO < 64) ? plo : phi;
      if (l == (wO & 63)) s_slotO[t & 1][w] = vO;
    }
    __syncthreads();                     // barrier B
  }

  // ---------------- fused output ----------------
  const float4* sbx = sboxes + (size_t)b * NB;
  const float* spb = sprob + (size_t)b * NB;
  for (int p = tid; p < NB; p += 512) {
    bool kp = false;
    if (p < K) {
      u64 wv = s_remv[p >> 6];
      kp = !((wv >> (p & 63)) & 1ull);
    }
    float4 bv = sbx[p];
    if (!kp) { bv.x = 0.0f; bv.y = 0.0f; bv.z = 0.0f; bv.w = 0.0f; }
    ((float4*)out)[(size_t)b * NB + p] = bv;
    out[(size_t)BIMG * NB * 4 + (size_t)b * NB + p] = kp ? spb[p] : 0.0f;
    out[(size_t)BIMG * NB * 5 + (size_t)b * NB + p] = kp ? 1.0f : 0.0f;
  }
}

// ---------------------------------------------------------------------------
// Fallback NMS kernel (used only if workspace is too small)
// ---------------------------------------------------------------------------
__global__ __launch_bounds__(1024) void nms_kernel(const float4* __restrict__ sboxes,
                                                   const float* __restrict__ sprob,
                                                   const u32* __restrict__ kcount,
                                                   float* __restrict__ out) {
  __shared__ float4 sb[NB];
  __shared__ unsigned char flag[NB];
  const int b = blockIdx.x;
  const int t = threadIdx.x;
  const int K = (int)kcount[b];

  for (int p = t; p < NB; p += 1024) {
    sb[p] = sboxes[(size_t)b * NB + p];
    flag[p] = (p < K) ? (unsigned char)0 : (unsigned char)1;
  }
  __syncthreads();

  for (int i = 0; i < K; ++i) {
    if (flag[i]) continue;
    float4 bi = sb[i];
    float area_i = (bi.z - bi.x) * (bi.w - bi.y);
    for (int j = i + 1 + t; j < K; j += 1024) {
      float4 bj = sb[j];
      float lx = fmaxf(bi.x, bj.x);
      float ly = fmaxf(bi.y, bj.y);
      float rx = fminf(bi.z, bj.z);
      float ry = fminf(bi.w, bj.w);
      float iw = fmaxf(rx - lx, 0.0f);
      float ih = fmaxf(ry - ly, 0.0f);
      float inter = iw * ih;
      float area_j = (bj.z - bj.x) * (bj.w - bj.y);
      float iou = inter / (area_i + area_j - inter);
      if (iou > 0.5f) flag[j] = (unsigned char)1;
    }
    __syncthreads();
  }

  float4* oboxes = (float4*)(out) + (size_t)b * NB;
  float* oscores = out + (size_t)BIMG * NB * 4 + (size_t)b * NB;
  float* okeep   = out + (size_t)BIMG * NB * 5 + (size_t)b * NB;
  for (int p = t; p < NB; p += 1024) {
    bool kp = (p < K) && (flag[p] == 0);
    float4 bv = sb[p];
    if (!kp) { bv.x = 0.0f; bv.y = 0.0f; bv.z = 0.0f; bv.w = 0.0f; }
    oboxes[p] = bv;
    oscores[p] = kp ? sprob[(size_t)b * NB + p] : 0.0f;
    okeep[p] = kp ? 1.0f : 0.0f;
  }
}

// ---------------------------------------------------------------------------
extern "C" void kernel_launch(void* const* d_in, const int* in_sizes, int n_in,
                              void* d_out, int out_size, void* d_ws, size_t ws_size,
                              hipStream_t stream) {
  const float* offsets = (const float*)d_in[0];   // [B,N,4] f32
  const float* labels  = (const float*)d_in[1];   // [B,N,1] f32
  const float* anchors = (const float*)d_in[2];   // [N,4]   f32
  float* out = (float*)d_out;

  char* ws = (char*)d_ws;
  u32*    kcount = (u32*)(ws + WS_KCOUNT);
  float4* boxes  = (float4*)(ws + WS_BOXES);
  float*  prob   = (float*)(ws + WS_PROB);
  float4* sboxes = (float4*)(ws + WS_SBOXES);
  float*  sprob  = (float*)(ws + WS_SPROB);

  sort_kernel<<<BIMG, 1024, 0, stream>>>(offsets, labels, anchors,
                                         boxes, prob, sboxes, sprob, kcount);

  if (ws_size >= WS_NEEDED) {
    u64*    mask   = (u64*)(ws + WS_MASK);
    unsigned char* rownz = (unsigned char*)(ws + WS_ROWNZ);
    u64*    diag   = (u64*)(ws + WS_DIAG);
    u64*    diag2  = (u64*)(ws + WS_DIAG2);

    mask_kernel<<<dim3(NB, BIMG), 256, 0, stream>>>(sboxes, kcount, mask, rownz,
                                                    diag, diag2);

    scan_kernel<<<BIMG, 512, 0, stream>>>(mask, diag, diag2, rownz, kcount,
                                          sboxes, sprob, out);
  } else {
    nms_kernel<<<BIMG, 1024, 0, stream>>>(sboxes, sprob, kcount, out);
  }
}

// Round 17
// 161.925 us; speedup vs baseline: 1.7943x; 1.2820x over previous
//
#include <hip/hip_runtime.h>
#include <cstdint>
#include <cstddef>

typedef unsigned int u32;
typedef unsigned long long u64;

#define NB 8192
#define BIMG 2
#define WPR (NB / 64)   // 128 u64 words per mask row

// ---------------- workspace layout (bytes) ----------------
#define WS_KCOUNT 0
#define WS_KEYS   256
#define WS_BOXES  (WS_KEYS + BIMG * NB * 8)          // 131328
#define WS_PROB   (WS_BOXES + BIMG * NB * 16)        // 393472
#define WS_SBOXES (WS_PROB + BIMG * NB * 4)          // 459008
#define WS_SPROB  (WS_SBOXES + BIMG * NB * 16)       // 721152
#define WS_REMV   (WS_SPROB + BIMG * NB * 4)         // 786688 (unused in fast path)
#define WS_MASK   (WS_REMV + BIMG * WPR * 8 + 256)   // 788992 (pad)
#define WS_ROWNZ  (WS_MASK + (size_t)BIMG * NB * WPR * 8)
#define WS_DIAG   (WS_ROWNZ + (size_t)BIMG * NB)         // 8-aligned
#define WS_DIAG2  (WS_DIAG + (size_t)BIMG * NB * 8)
#define WS_NEEDED (WS_DIAG2 + (size_t)BIMG * NB * 8)     // ~17.9 MB

__device__ inline u64 rdl64(u64 v, int lane) {
  u32 lo = (u32)__builtin_amdgcn_readlane((int)(u32)v, lane);
  u32 hi = (u32)__builtin_amdgcn_readlane((int)(u32)(v >> 32), lane);
  return ((u64)hi << 32) | lo;
}

__device__ inline u64 shflxor64(u64 v, int off) {
  u32 lo = (u32)v, hi = (u32)(v >> 32);
  lo = (u32)__shfl_xor((int)lo, off, 64);
  hi = (u32)__shfl_xor((int)hi, off, 64);
  return ((u64)hi << 32) | lo;
}

// ---------------------------------------------------------------------------
// Kernel 1: sigmoid + box decode + sort-key build (no atomics; r11 form)
// ---------------------------------------------------------------------------
__global__ void decode_kernel(const float* __restrict__ offsets,
                              const float* __restrict__ labels,
                              const float* __restrict__ anchors,
                              u64* __restrict__ keys,
                              float4* __restrict__ boxes,
                              float* __restrict__ prob) {
  int idx = blockIdx.x * blockDim.x + threadIdx.x;
  if (idx >= BIMG * NB) return;
  int n = idx & (NB - 1);

  float logit = labels[idx];
  float p = 1.0f / (1.0f + expf(-logit));
  bool valid = p > 0.5f;

  const float4 an = ((const float4*)anchors)[n];   // x1,y1,x2,y2
  float acx = (an.x + an.z) / 2.0f;
  float acy = (an.y + an.w) / 2.0f;
  float aw = an.z - an.x;
  float ah = an.w - an.y;

  const float4 of = ((const float4*)offsets)[idx]; // gcx,gcy,gw,gh
  float cx = of.x * aw / 10.0f + acx;
  float cy = of.y * ah / 10.0f + acy;
  float w = expf(of.z / 5.0f) * aw;
  float h = expf(of.w / 5.0f) * ah;

  float4 bx;
  bx.x = cx - w / 2.0f;
  bx.y = cy - h / 2.0f;
  bx.z = cx + w / 2.0f;
  bx.w = cy + h / 2.0f;
  boxes[idx] = bx;
  prob[idx] = p;

  u32 e = valid ? (__float_as_uint(p) ^ 0x80000000u) : 0u;
  keys[idx] = ((u64)e << 32) | (u32)(~(u32)n);
}

// ---------------------------------------------------------------------------
// Kernel 2: RANK-SORT. rank(i) = #{k : key[k] > key[i]} (keys unique ->
// rank == stable argsort-desc position). Only valid elements are scattered;
// positions >= K stay unwritten (provably unobservable: every consumer
// gates on < K). Each block redundantly computes K from its full key sweep
// (zero atomics); block 0 writes kcount.
// Grid: (NB/64) x BIMG, 512 threads. Lane l owns element i0+l; wave w owns
// key range [w*1024,(w+1)*1024) staged in a wave-private LDS tile.
// ---------------------------------------------------------------------------
__global__ __launch_bounds__(512) void rank_kernel(const u64* __restrict__ keys,
                                                   const float4* __restrict__ boxes,
                                                   const float* __restrict__ prob,
                                                   float4* __restrict__ sboxes,
                                                   float* __restrict__ sprob,
                                                   u32* __restrict__ kcount) {
  __shared__ u64 s_buf[8][64];     // wave-private tiles (4 KB)
  __shared__ u32 s_cnt[64][9];     // padded: stride 9 -> conflict-free
  __shared__ u32 s_v[8];
  const int b = blockIdx.y;
  const int i0 = blockIdx.x * 64;
  const int w = threadIdx.x >> 6;
  const int lane = threadIdx.x & 63;
  const u64* kb = keys + (size_t)b * NB;

  const u64 myk = kb[i0 + lane];   // same 64 values per wave (L1 broadcast)
  u32 cnt = 0, vcnt = 0;
  for (int t = 0; t < 16; ++t) {
    s_buf[w][lane] = kb[w * 1024 + t * 64 + lane];   // wave-private: no barrier
    u32 c0 = 0, c1 = 0, c2 = 0, c3 = 0, v0 = 0;
#pragma unroll
    for (int jj = 0; jj < 64; jj += 4) {
      u64 k0 = s_buf[w][jj + 0];
      u64 k1 = s_buf[w][jj + 1];
      u64 k2 = s_buf[w][jj + 2];
      u64 k3 = s_buf[w][jj + 3];
      c0 += (k0 > myk) ? 1u : 0u;
      c1 += (k1 > myk) ? 1u : 0u;
      c2 += (k2 > myk) ? 1u : 0u;
      c3 += (k3 > myk) ? 1u : 0u;
      v0 += (((u32)(k0 >> 32)) != 0u) ? 1u : 0u;
      v0 += (((u32)(k1 >> 32)) != 0u) ? 1u : 0u;
      v0 += (((u32)(k2 >> 32)) != 0u) ? 1u : 0u;
      v0 += (((u32)(k3 >> 32)) != 0u) ? 1u : 0u;
    }
    cnt += c0 + c1 + c2 + c3;
    vcnt += v0;
  }
  s_cnt[lane][w] = cnt;
  if (lane == 0) s_v[w] = vcnt;
  __syncthreads();

  if (threadIdx.x < 64) {
    int i = i0 + threadIdx.x;           // == i0 + lane for wave 0
    u32 rank = 0;
#pragma unroll
    for (int q = 0; q < 8; ++q) rank += s_cnt[threadIdx.x][q];
    bool valid = ((u32)(myk >> 32)) != 0u;
    if (valid) {
      sboxes[(size_t)b * NB + rank] = boxes[(size_t)b * NB + i];
      sprob[(size_t)b * NB + rank]  = prob[(size_t)b * NB + i];
    }
  }
  if (blockIdx.x == 0 && threadIdx.x == 0) {
    u32 K = 0;
#pragma unroll
    for (int q = 0; q < 8; ++q) K += s_v[q];
    kcount[b] = K;
  }
}

// ---------------------------------------------------------------------------
// Kernel 4: overlap bitmask build (r16 form — best measured, tc>>2 trim).
// ---------------------------------------------------------------------------
__global__ __launch_bounds__(256) void mask_kernel(const float4* __restrict__ sboxes,
                                                   const u32* __restrict__ kcount,
                                                   u64* __restrict__ mask,
                                                   unsigned char* __restrict__ rownz,
                                                   u64* __restrict__ diag,
                                                   u64* __restrict__ diag2) {
  const int i = blockIdx.x;       // sorted row
  const int b = blockIdx.y;
  const int K = (int)kcount[b];
  if (i >= K) return;
  const int wave = threadIdx.x >> 6;
  const int lane = threadIdx.x & 63;
  const int tc = i >> 6;
  __shared__ u32 anyf[4];
  const float4* sb = sboxes + (size_t)b * NB;
  const float4 bi = sb[i];
  const float area_i = (bi.z - bi.x) * (bi.w - bi.y);
  u64* mrow = mask + ((size_t)b * NB + i) * WPR;
  bool any = false;
  for (int pass = tc >> 2; pass < WPR / 4; ++pass) {
    int w = pass * 4 + wave;
    u64 word = 0;
    bool act = ((w + 1) * 64 > i) && (w * 64 < K);   // uniform per wave
    if (act) {
      int j = w * 64 + lane;
      float4 bj = sb[j];
      float lx = fmaxf(bi.x, bj.x);
      float ly = fmaxf(bi.y, bj.y);
      float rx = fminf(bi.z, bj.z);
      float ry = fminf(bi.w, bj.w);
      float iw = fmaxf(rx - lx, 0.0f);
      float ih = fmaxf(ry - ly, 0.0f);
      float inter = iw * ih;
      float area_j = (bj.z - bj.x) * (bj.w - bj.y);
      float iou = inter / (area_i + area_j - inter);
      bool pred = (j > i) && (j < K) && (iou > 0.5f);
      word = __ballot(pred);
      any = any || (word != 0ull);
    }
    if (lane == 0) {
      if (act) mrow[w] = word;
      if (w == tc)          diag[(size_t)b * NB + i]  = word;
      else if (w == tc + 1) diag2[(size_t)b * NB + i] = word;   // 0 if !act
    }
  }
  if (lane == 0) anyf[wave] = any ? 1u : 0u;
  __syncthreads();
  if (threadIdx.x == 0) {
    u32 a = anyf[0] | anyf[1] | anyf[2] | anyf[3];
    rownz[(size_t)b * NB + i] = (unsigned char)(a ? 1 : 0);
  }
}

// ---------------------------------------------------------------------------
// Kernel 5: PAIRED chunked greedy scan + fused output (r16, verified 92us).
// ---------------------------------------------------------------------------
#define SCAN_WAVES 8
#define MAXROWS 10

__device__ inline void resolve_diag(u64& rc, u64 dw) {
  u64 nzd = __ballot(dw != 0ull) & ~rc;
  while (nzd) {
    int tt = __builtin_ctzll(nzd);
    rc |= rdl64(dw, tt);
    nzd &= ~(1ull << tt) & ~rc;
  }
}

__global__ __launch_bounds__(512) void scan_kernel(const u64* __restrict__ mask,
                                                   const u64* __restrict__ diag,
                                                   const u64* __restrict__ diag2,
                                                   const unsigned char* __restrict__ rownz,
                                                   const u32* __restrict__ kcount,
                                                   const float4* __restrict__ sboxes,
                                                   const float* __restrict__ sprob,
                                                   float* __restrict__ out) {
  __shared__ u64 s_remv[WPR];               // finalized rc words (1 KB)
  __shared__ u64 s_slotE[2][SCAN_WAVES];    // posts of word 2t+2
  __shared__ u64 s_slotO[2][SCAN_WAVES];    // posts of word 2t+3
  __shared__ u64 s_kuA, s_kuB, s_nzwA, s_nzwB;
  const int b = blockIdx.x;
  const int tid = threadIdx.x;
  const int w = tid >> 6;                   // wave id 0..7
  const int l = tid & 63;
  const int K = (int)kcount[b];
  const u64* mb = mask + (size_t)b * NB * WPR;
  const u64* dg = diag + (size_t)b * NB;
  const u64* dg2 = diag2 + (size_t)b * NB;
  const unsigned char* nzb = rownz + (size_t)b * NB;
  const int NC = min(WPR, (K + 63) >> 6);
  const int NCL = min(NC, 64);
  const int NP = (NC + 1) >> 1;             // chunk pairs

  if (tid < 2 * SCAN_WAVES) { ((u64*)s_slotE)[tid] = 0; ((u64*)s_slotO)[tid] = 0; }

  u64 plo = 0, phi = 0;
  const bool okLo = (l < NCL);
  const bool okHi = (64 + l) < NC;
  u64 LA[MAXROWS], HA[MAXROWS], LB[MAXROWS], HB[MAXROWS];
  u64 bqA[MAXROWS], bqB[MAXROWS];
  u64 dwA = 0, dwB = 0, cw = 0;
  unsigned char nzcA = 0, nzcB = 0;

  if (w == 0 && NP > 0) {
    int rA = l, rB = 64 + l;
    dwA = (rA < K) ? dg[rA] : 0ull;
    dwB = (rB < K) ? dg[rB] : 0ull;
    cw  = (rA < K) ? dg2[rA] : 0ull;
    nzcA = (rA < K) ? nzb[rA] : (unsigned char)0;
    nzcB = (rB < K) ? nzb[rB] : (unsigned char)0;
    u64 a0 = __ballot(nzcA != 0), b0 = __ballot(nzcB != 0);
    if (l == 0) { s_nzwA = a0; s_nzwB = b0; }
  }
  __syncthreads();

  for (int t = 0; t < NP; ++t) {
    const int cA = 2 * t, cB = 2 * t + 1;
    const bool hasB = (cB < NC);
    // ---------------- phase 1 ----------------
    if (w == 0) {
      u64 dwA_n = 0, dwB_n = 0, cw_n = 0;
      unsigned char nzA_n = 0, nzB_n = 0;
      if (t + 1 < NP) {
        int rA = (t + 1) * 128 + l, rB = (t + 1) * 128 + 64 + l;
        dwA_n = (rA < K) ? dg[rA] : 0ull;
        dwB_n = (rB < K) ? dg[rB] : 0ull;
        cw_n  = (rA < K) ? dg2[rA] : 0ull;
        nzA_n = (rA < K) ? nzb[rA] : (unsigned char)0;
        nzB_n = (rB < K) ? nzb[rB] : (unsigned char)0;
      }
      int pr = (t + 1) & 1;
      u64 valA = s_slotE[pr][l & (SCAN_WAVES - 1)];
      u64 valB = s_slotO[pr][l & (SCAN_WAVES - 1)];
#pragma unroll
      for (int off = 1; off < SCAN_WAVES; off <<= 1) {
        valA |= shflxor64(valA, off);
        valB |= shflxor64(valB, off);
      }
      int loA = cA * 64;
      u64 tailA = (loA + 64 <= K) ? 0ull : ((~0ull) << (K - loA));
      u64 rcA = valA | tailA;
      u64 nzwA = __ballot(nzcA != 0);
      resolve_diag(rcA, dwA);
      u64 kuA = (~rcA) & nzwA;
      u64 m = ((~rcA >> l) & 1ull) ? cw : 0ull;
#pragma unroll
      for (int off = 32; off > 0; off >>= 1) m |= shflxor64(m, off);
      u64 rcB = ~0ull, kuB = 0;
      if (hasB) {
        int loB = cB * 64;
        u64 tailB = (loB + 64 <= K) ? 0ull : ((~0ull) << (K - loB));
        rcB = valB | tailB | m;
        u64 nzwB = __ballot(nzcB != 0);
        resolve_diag(rcB, dwB);
        kuB = (~rcB) & nzwB;
      }
      if (l == 0) {
        s_remv[cA] = rcA;
        if (hasB) s_remv[cB] = rcB;
        s_kuA = kuA; s_kuB = kuB;
      }
      dwA = dwA_n; dwB = dwB_n; cw = cw_n; nzcA = nzA_n; nzcB = nzB_n;
    } else {
      u64 kkA = (s_nzwA >> ((w - 1) * MAXROWS)) & ((1ull << MAXROWS) - 1ull);
      u64 kkB = (s_nzwB >> ((w - 1) * MAXROWS)) & ((1ull << MAXROWS) - 1ull);
#pragma unroll
      for (int q = 0; q < MAXROWS; ++q) {
        bool hA = (kkA != 0ull);
        int tA = hA ? __builtin_ctzll(kkA) : 0;
        if (hA) kkA &= kkA - 1;
        bqA[q] = hA ? (1ull << ((w - 1) * MAXROWS + tA)) : 0ull;
        LA[q] = 0; HA[q] = 0;
        if (hA) {
          const u64* rp = mb + (size_t)(cA * 64 + (w - 1) * MAXROWS + tA) * WPR;
          if (okLo) LA[q] = rp[l];
          if (okHi) HA[q] = rp[64 + l];
        }
        bool hB = (kkB != 0ull);
        int tB = hB ? __builtin_ctzll(kkB) : 0;
        if (hB) kkB &= kkB - 1;
        bqB[q] = hB ? (1ull << ((w - 1) * MAXROWS + tB)) : 0ull;
        LB[q] = 0; HB[q] = 0;
        if (hB) {
          const u64* rp = mb + (size_t)(cB * 64 + (w - 1) * MAXROWS + tB) * WPR;
          if (okLo) LB[q] = rp[l];
          if (okHi) HB[q] = rp[64 + l];
        }
      }
    }
    __syncthreads();                     // barrier A

    // ---------------- phase 2 (register/LDS only) ----------------
    if (w == 0) {
      u64 a1 = __ballot(nzcA != 0), b1 = __ballot(nzcB != 0);
      if (l == 0) { s_nzwA = a1; s_nzwB = b1; }
    } else {
      u64 kuA = s_kuA, kuB = s_kuB;
#pragma unroll
      for (int q = 0; q < MAXROWS; ++q) {
        if (kuA & bqA[q]) { plo |= LA[q]; phi |= HA[q]; }
        if (kuB & bqB[q]) { plo |= LB[q]; phi |= HB[q]; }
      }
      int wE = cA + 2, wO = cA + 3;
      u64 vE = (wE < 64) ? plo : phi;
      if (l == (wE & 63)) s_slotE[t & 1][w] = vE;
      u64 vO = (wO < 64) ? plo : phi;
      if (l == (wO & 63)) s_slotO[t & 1][w] = vO;
    }
    __syncthreads();                     // barrier B
  }

  // ---------------- fused output ----------------
  const float4* sbx = sboxes + (size_t)b * NB;
  const float* spb = sprob + (size_t)b * NB;
  for (int p = tid; p < NB; p += 512) {
    bool kp = false;
    if (p < K) {
      u64 wv = s_remv[p >> 6];
      kp = !((wv >> (p & 63)) & 1ull);
    }
    float4 bv = sbx[p];
    if (!kp) { bv.x = 0.0f; bv.y = 0.0f; bv.z = 0.0f; bv.w = 0.0f; }
    ((float4*)out)[(size_t)b * NB + p] = bv;
    out[(size_t)BIMG * NB * 4 + (size_t)b * NB + p] = kp ? spb[p] : 0.0f;
    out[(size_t)BIMG * NB * 5 + (size_t)b * NB + p] = kp ? 1.0f : 0.0f;
  }
}

// ---------------------------------------------------------------------------
// Fallback NMS kernel (used only if workspace is too small)
// ---------------------------------------------------------------------------
__global__ __launch_bounds__(1024) void nms_kernel(const float4* __restrict__ sboxes,
                                                   const float* __restrict__ sprob,
                                                   const u32* __restrict__ kcount,
                                                   float* __restrict__ out) {
  __shared__ float4 sb[NB];
  __shared__ unsigned char flag[NB];
  const int b = blockIdx.x;
  const int t = threadIdx.x;
  const int K = (int)kcount[b];

  for (int p = t; p < NB; p += 1024) {
    sb[p] = sboxes[(size_t)b * NB + p];
    flag[p] = (p < K) ? (unsigned char)0 : (unsigned char)1;
  }
  __syncthreads();

  for (int i = 0; i < K; ++i) {
    if (flag[i]) continue;
    float4 bi = sb[i];
    float area_i = (bi.z - bi.x) * (bi.w - bi.y);
    for (int j = i + 1 + t; j < K; j += 1024) {
      float4 bj = sb[j];
      float lx = fmaxf(bi.x, bj.x);
      float ly = fmaxf(bi.y, bj.y);
      float rx = fminf(bi.z, bj.z);
      float ry = fminf(bi.w, bj.w);
      float iw = fmaxf(rx - lx, 0.0f);
      float ih = fmaxf(ry - ly, 0.0f);
      float inter = iw * ih;
      float area_j = (bj.z - bj.x) * (bj.w - bj.y);
      float iou = inter / (area_i + area_j - inter);
      if (iou > 0.5f) flag[j] = (unsigned char)1;
    }
    __syncthreads();
  }

  float4* oboxes = (float4*)(out) + (size_t)b * NB;
  float* oscores = out + (size_t)BIMG * NB * 4 + (size_t)b * NB;
  float* okeep   = out + (size_t)BIMG * NB * 5 + (size_t)b * NB;
  for (int p = t; p < NB; p += 1024) {
    bool kp = (p < K) && (flag[p] == 0);
    float4 bv = sb[p];
    if (!kp) { bv.x = 0.0f; bv.y = 0.0f; bv.z = 0.0f; bv.w = 0.0f; }
    oboxes[p] = bv;
    oscores[p] = kp ? sprob[(size_t)b * NB + p] : 0.0f;
    okeep[p] = kp ? 1.0f : 0.0f;
  }
}

// ---------------------------------------------------------------------------
extern "C" void kernel_launch(void* const* d_in, const int* in_sizes, int n_in,
                              void* d_out, int out_size, void* d_ws, size_t ws_size,
                              hipStream_t stream) {
  const float* offsets = (const float*)d_in[0];   // [B,N,4] f32
  const float* labels  = (const float*)d_in[1];   // [B,N,1] f32
  const float* anchors = (const float*)d_in[2];   // [N,4]   f32
  float* out = (float*)d_out;

  char* ws = (char*)d_ws;
  u32*    kcount = (u32*)(ws + WS_KCOUNT);
  u64*    keys   = (u64*)(ws + WS_KEYS);
  float4* boxes  = (float4*)(ws + WS_BOXES);
  float*  prob   = (float*)(ws + WS_PROB);
  float4* sboxes = (float4*)(ws + WS_SBOXES);
  float*  sprob  = (float*)(ws + WS_SPROB);

  int total = BIMG * NB;
  decode_kernel<<<(total + 255) / 256, 256, 0, stream>>>(
      offsets, labels, anchors, keys, boxes, prob);

  rank_kernel<<<dim3(NB / 64, BIMG), 512, 0, stream>>>(
      keys, boxes, prob, sboxes, sprob, kcount);

  if (ws_size >= WS_NEEDED) {
    u64*    mask   = (u64*)(ws + WS_MASK);
    unsigned char* rownz = (unsigned char*)(ws + WS_ROWNZ);
    u64*    diag   = (u64*)(ws + WS_DIAG);
    u64*    diag2  = (u64*)(ws + WS_DIAG2);

    mask_kernel<<<dim3(NB, BIMG), 256, 0, stream>>>(sboxes, kcount, mask, rownz,
                                                    diag, diag2);

    scan_kernel<<<BIMG, 512, 0, stream>>>(mask, diag, diag2, rownz, kcount,
                                          sboxes, sprob, out);
  } else {
    nms_kernel<<<BIMG, 1024, 0, stream>>>(sboxes, sprob, kcount, out);
  }
}

// Round 18
// 151.940 us; speedup vs baseline: 1.9122x; 1.0657x over previous
//
#include <hip/hip_runtime.h>
#include <cstdint>
#include <cstddef>

typedef unsigned int u32;
typedef unsigned long long u64;

#define NB 8192
#define BIMG 2
#define WPR (NB / 64)   // 128 u64 words per mask row

// ---------------- workspace layout (bytes) ----------------
#define WS_KCOUNT 0
#define WS_KEYS   256
#define WS_BOXES  (WS_KEYS + BIMG * NB * 8)          // 131328
#define WS_PROB   (WS_BOXES + BIMG * NB * 16)        // 393472
#define WS_SBOXES (WS_PROB + BIMG * NB * 4)          // 459008
#define WS_SPROB  (WS_SBOXES + BIMG * NB * 16)       // 721152
#define WS_REMV   (WS_SPROB + BIMG * NB * 4)         // 786688 (unused in fast path)
#define WS_MASK   (WS_REMV + BIMG * WPR * 8 + 256)   // 788992 (pad)
#define WS_ROWNZ  (WS_MASK + (size_t)BIMG * NB * WPR * 8)
#define WS_DIAG   (WS_ROWNZ + (size_t)BIMG * NB)         // 8-aligned
#define WS_DIAG2  (WS_DIAG + (size_t)BIMG * NB * 8)
#define WS_NEEDED (WS_DIAG2 + (size_t)BIMG * NB * 8)     // ~17.9 MB

__device__ inline u64 rdl64(u64 v, int lane) {
  u32 lo = (u32)__builtin_amdgcn_readlane((int)(u32)v, lane);
  u32 hi = (u32)__builtin_amdgcn_readlane((int)(u32)(v >> 32), lane);
  return ((u64)hi << 32) | lo;
}

__device__ inline u64 shflxor64(u64 v, int off) {
  u32 lo = (u32)v, hi = (u32)(v >> 32);
  lo = (u32)__shfl_xor((int)lo, off, 64);
  hi = (u32)__shfl_xor((int)hi, off, 64);
  return ((u64)hi << 32) | lo;
}

// ---------------------------------------------------------------------------
// Kernel 1: sigmoid + box decode + sort-key build (no atomics; r11 form)
// ---------------------------------------------------------------------------
__global__ void decode_kernel(const float* __restrict__ offsets,
                              const float* __restrict__ labels,
                              const float* __restrict__ anchors,
                              u64* __restrict__ keys,
                              float4* __restrict__ boxes,
                              float* __restrict__ prob) {
  int idx = blockIdx.x * blockDim.x + threadIdx.x;
  if (idx >= BIMG * NB) return;
  int n = idx & (NB - 1);

  float logit = labels[idx];
  float p = 1.0f / (1.0f + expf(-logit));
  bool valid = p > 0.5f;

  const float4 an = ((const float4*)anchors)[n];   // x1,y1,x2,y2
  float acx = (an.x + an.z) / 2.0f;
  float acy = (an.y + an.w) / 2.0f;
  float aw = an.z - an.x;
  float ah = an.w - an.y;

  const float4 of = ((const float4*)offsets)[idx]; // gcx,gcy,gw,gh
  float cx = of.x * aw / 10.0f + acx;
  float cy = of.y * ah / 10.0f + acy;
  float w = expf(of.z / 5.0f) * aw;
  float h = expf(of.w / 5.0f) * ah;

  float4 bx;
  bx.x = cx - w / 2.0f;
  bx.y = cy - h / 2.0f;
  bx.z = cx + w / 2.0f;
  bx.w = cy + h / 2.0f;
  boxes[idx] = bx;
  prob[idx] = p;

  u32 e = valid ? (__float_as_uint(p) ^ 0x80000000u) : 0u;
  keys[idx] = ((u64)e << 32) | (u32)(~(u32)n);
}

// ---------------------------------------------------------------------------
// Kernel 2: RANK-SORT (r17, verified). rank(i) = #{k : key[k] > key[i]}.
// ---------------------------------------------------------------------------
__global__ __launch_bounds__(512) void rank_kernel(const u64* __restrict__ keys,
                                                   const float4* __restrict__ boxes,
                                                   const float* __restrict__ prob,
                                                   float4* __restrict__ sboxes,
                                                   float* __restrict__ sprob,
                                                   u32* __restrict__ kcount) {
  __shared__ u64 s_buf[8][64];     // wave-private tiles (4 KB)
  __shared__ u32 s_cnt[64][9];     // padded: stride 9 -> conflict-free
  __shared__ u32 s_v[8];
  const int b = blockIdx.y;
  const int i0 = blockIdx.x * 64;
  const int w = threadIdx.x >> 6;
  const int lane = threadIdx.x & 63;
  const u64* kb = keys + (size_t)b * NB;

  const u64 myk = kb[i0 + lane];   // same 64 values per wave (L1 broadcast)
  u32 cnt = 0, vcnt = 0;
  for (int t = 0; t < 16; ++t) {
    s_buf[w][lane] = kb[w * 1024 + t * 64 + lane];   // wave-private: no barrier
    u32 c0 = 0, c1 = 0, c2 = 0, c3 = 0, v0 = 0;
#pragma unroll
    for (int jj = 0; jj < 64; jj += 4) {
      u64 k0 = s_buf[w][jj + 0];
      u64 k1 = s_buf[w][jj + 1];
      u64 k2 = s_buf[w][jj + 2];
      u64 k3 = s_buf[w][jj + 3];
      c0 += (k0 > myk) ? 1u : 0u;
      c1 += (k1 > myk) ? 1u : 0u;
      c2 += (k2 > myk) ? 1u : 0u;
      c3 += (k3 > myk) ? 1u : 0u;
      v0 += (((u32)(k0 >> 32)) != 0u) ? 1u : 0u;
      v0 += (((u32)(k1 >> 32)) != 0u) ? 1u : 0u;
      v0 += (((u32)(k2 >> 32)) != 0u) ? 1u : 0u;
      v0 += (((u32)(k3 >> 32)) != 0u) ? 1u : 0u;
    }
    cnt += c0 + c1 + c2 + c3;
    vcnt += v0;
  }
  s_cnt[lane][w] = cnt;
  if (lane == 0) s_v[w] = vcnt;
  __syncthreads();

  if (threadIdx.x < 64) {
    int i = i0 + threadIdx.x;           // == i0 + lane for wave 0
    u32 rank = 0;
#pragma unroll
    for (int q = 0; q < 8; ++q) rank += s_cnt[threadIdx.x][q];
    bool valid = ((u32)(myk >> 32)) != 0u;
    if (valid) {
      sboxes[(size_t)b * NB + rank] = boxes[(size_t)b * NB + i];
      sprob[(size_t)b * NB + rank]  = prob[(size_t)b * NB + i];
    }
  }
  if (blockIdx.x == 0 && threadIdx.x == 0) {
    u32 K = 0;
#pragma unroll
    for (int q = 0; q < 8; ++q) K += s_v[q];
    kcount[b] = K;
  }
}

// ---------------------------------------------------------------------------
// Kernel 4: overlap bitmask build — 8-ROW TILES with bj reuse.
// Block = 8 consecutive sorted rows (one shared tc since 8 | 64); grid
// (NB/8) x BIMG, 256 thr (4 waves). Wave wv handles words w = tc+wv, +4, ...
// Per word: lane loads bj ONCE, computes 8 independent IoUs (one per row,
// bi via LDS broadcast), 8 ballots amortized against 8x15 VALU. Write-set /
// predicate / IoU expression identical to the proven r16 mask; diag2 written
// iff tc+1 < NC (the only case it is ever consumed).
// ---------------------------------------------------------------------------
#define MROWS 8

__global__ __launch_bounds__(256) void mask_kernel(const float4* __restrict__ sboxes,
                                                   const u32* __restrict__ kcount,
                                                   u64* __restrict__ mask,
                                                   unsigned char* __restrict__ rownz,
                                                   u64* __restrict__ diag,
                                                   u64* __restrict__ diag2) {
  const int b = blockIdx.y;
  const int K = (int)kcount[b];
  const int i0 = blockIdx.x * MROWS;
  if (i0 >= K) return;
  const int wv = threadIdx.x >> 6;     // wave 0..3
  const int lane = threadIdx.x & 63;
  const int tc = i0 >> 6;              // same chunk for all 8 rows
  const int NC = min(WPR, (K + 63) >> 6);
  __shared__ float4 s_bi[MROWS];
  __shared__ float s_ai[MROWS];
  __shared__ u32 s_anyw[4];
  if (threadIdx.x < MROWS) {
    float4 v = sboxes[(size_t)b * NB + i0 + threadIdx.x];
    s_bi[threadIdx.x] = v;
    s_ai[threadIdx.x] = (v.z - v.x) * (v.w - v.y);
  }
  __syncthreads();

  const float4* sb = sboxes + (size_t)b * NB;
  u64* mbase = mask + (size_t)b * NB * WPR;
  u32 anyr = 0;                        // bit r: row i0+r has a nonzero word

  for (int w = tc + wv; w < NC; w += 4) {
    const int j = w * 64 + lane;
    const float4 bj = sb[j];
    const float area_j = (bj.z - bj.x) * (bj.w - bj.y);
    u64 words[MROWS];
#pragma unroll
    for (int r = 0; r < MROWS; ++r) {
      float4 bi = s_bi[r];
      float lx = fmaxf(bi.x, bj.x);
      float ly = fmaxf(bi.y, bj.y);
      float rx = fminf(bi.z, bj.z);
      float ry = fminf(bi.w, bj.w);
      float iw = fmaxf(rx - lx, 0.0f);
      float ih = fmaxf(ry - ly, 0.0f);
      float inter = iw * ih;
      float iou = inter / (s_ai[r] + area_j - inter);
      bool pred = (j > i0 + r) && (j < K) && (iou > 0.5f);
      words[r] = __ballot(pred);
    }
#pragma unroll
    for (int r = 0; r < MROWS; ++r) anyr |= (words[r] != 0ull) ? (1u << r) : 0u;
    if (lane == 0) {
#pragma unroll
      for (int r = 0; r < MROWS; ++r) {
        int i = i0 + r;
        if (i < K) {
          mbase[(size_t)i * WPR + w] = words[r];
          if (w == tc)          diag[(size_t)b * NB + i]  = words[r];
          else if (w == tc + 1) diag2[(size_t)b * NB + i] = words[r];
        }
      }
    }
  }
  if (lane == 0) s_anyw[wv] = anyr;
  __syncthreads();
  if (threadIdx.x < MROWS) {
    int i = i0 + threadIdx.x;
    if (i < K) {
      u32 a = (s_anyw[0] | s_anyw[1] | s_anyw[2] | s_anyw[3]) >> threadIdx.x;
      rownz[(size_t)b * NB + i] = (unsigned char)(a & 1u);
    }
  }
}

// ---------------------------------------------------------------------------
// Kernel 5: PAIRED chunked greedy scan + fused output (r16, verified 92us).
// ---------------------------------------------------------------------------
#define SCAN_WAVES 8
#define MAXROWS 10

__device__ inline void resolve_diag(u64& rc, u64 dw) {
  u64 nzd = __ballot(dw != 0ull) & ~rc;
  while (nzd) {
    int tt = __builtin_ctzll(nzd);
    rc |= rdl64(dw, tt);
    nzd &= ~(1ull << tt) & ~rc;
  }
}

__global__ __launch_bounds__(512) void scan_kernel(const u64* __restrict__ mask,
                                                   const u64* __restrict__ diag,
                                                   const u64* __restrict__ diag2,
                                                   const unsigned char* __restrict__ rownz,
                                                   const u32* __restrict__ kcount,
                                                   const float4* __restrict__ sboxes,
                                                   const float* __restrict__ sprob,
                                                   float* __restrict__ out) {
  __shared__ u64 s_remv[WPR];               // finalized rc words (1 KB)
  __shared__ u64 s_slotE[2][SCAN_WAVES];    // posts of word 2t+2
  __shared__ u64 s_slotO[2][SCAN_WAVES];    // posts of word 2t+3
  __shared__ u64 s_kuA, s_kuB, s_nzwA, s_nzwB;
  const int b = blockIdx.x;
  const int tid = threadIdx.x;
  const int w = tid >> 6;                   // wave id 0..7
  const int l = tid & 63;
  const int K = (int)kcount[b];
  const u64* mb = mask + (size_t)b * NB * WPR;
  const u64* dg = diag + (size_t)b * NB;
  const u64* dg2 = diag2 + (size_t)b * NB;
  const unsigned char* nzb = rownz + (size_t)b * NB;
  const int NC = min(WPR, (K + 63) >> 6);
  const int NCL = min(NC, 64);
  const int NP = (NC + 1) >> 1;             // chunk pairs

  if (tid < 2 * SCAN_WAVES) { ((u64*)s_slotE)[tid] = 0; ((u64*)s_slotO)[tid] = 0; }

  u64 plo = 0, phi = 0;
  const bool okLo = (l < NCL);
  const bool okHi = (64 + l) < NC;
  u64 LA[MAXROWS], HA[MAXROWS], LB[MAXROWS], HB[MAXROWS];
  u64 bqA[MAXROWS], bqB[MAXROWS];
  u64 dwA = 0, dwB = 0, cw = 0;
  unsigned char nzcA = 0, nzcB = 0;

  if (w == 0 && NP > 0) {
    int rA = l, rB = 64 + l;
    dwA = (rA < K) ? dg[rA] : 0ull;
    dwB = (rB < K) ? dg[rB] : 0ull;
    cw  = (rA < K) ? dg2[rA] : 0ull;
    nzcA = (rA < K) ? nzb[rA] : (unsigned char)0;
    nzcB = (rB < K) ? nzb[rB] : (unsigned char)0;
    u64 a0 = __ballot(nzcA != 0), b0 = __ballot(nzcB != 0);
    if (l == 0) { s_nzwA = a0; s_nzwB = b0; }
  }
  __syncthreads();

  for (int t = 0; t < NP; ++t) {
    const int cA = 2 * t, cB = 2 * t + 1;
    const bool hasB = (cB < NC);
    // ---------------- phase 1 ----------------
    if (w == 0) {
      u64 dwA_n = 0, dwB_n = 0, cw_n = 0;
      unsigned char nzA_n = 0, nzB_n = 0;
      if (t + 1 < NP) {
        int rA = (t + 1) * 128 + l, rB = (t + 1) * 128 + 64 + l;
        dwA_n = (rA < K) ? dg[rA] : 0ull;
        dwB_n = (rB < K) ? dg[rB] : 0ull;
        cw_n  = (rA < K) ? dg2[rA] : 0ull;
        nzA_n = (rA < K) ? nzb[rA] : (unsigned char)0;
        nzB_n = (rB < K) ? nzb[rB] : (unsigned char)0;
      }
      int pr = (t + 1) & 1;
      u64 valA = s_slotE[pr][l & (SCAN_WAVES - 1)];
      u64 valB = s_slotO[pr][l & (SCAN_WAVES - 1)];
#pragma unroll
      for (int off = 1; off < SCAN_WAVES; off <<= 1) {
        valA |= shflxor64(valA, off);
        valB |= shflxor64(valB, off);
      }
      int loA = cA * 64;
      u64 tailA = (loA + 64 <= K) ? 0ull : ((~0ull) << (K - loA));
      u64 rcA = valA | tailA;
      u64 nzwA = __ballot(nzcA != 0);
      resolve_diag(rcA, dwA);
      u64 kuA = (~rcA) & nzwA;
      u64 m = ((~rcA >> l) & 1ull) ? cw : 0ull;
#pragma unroll
      for (int off = 32; off > 0; off >>= 1) m |= shflxor64(m, off);
      u64 rcB = ~0ull, kuB = 0;
      if (hasB) {
        int loB = cB * 64;
        u64 tailB = (loB + 64 <= K) ? 0ull : ((~0ull) << (K - loB));
        rcB = valB | tailB | m;
        u64 nzwB = __ballot(nzcB != 0);
        resolve_diag(rcB, dwB);
        kuB = (~rcB) & nzwB;
      }
      if (l == 0) {
        s_remv[cA] = rcA;
        if (hasB) s_remv[cB] = rcB;
        s_kuA = kuA; s_kuB = kuB;
      }
      dwA = dwA_n; dwB = dwB_n; cw = cw_n; nzcA = nzA_n; nzcB = nzB_n;
    } else {
      u64 kkA = (s_nzwA >> ((w - 1) * MAXROWS)) & ((1ull << MAXROWS) - 1ull);
      u64 kkB = (s_nzwB >> ((w - 1) * MAXROWS)) & ((1ull << MAXROWS) - 1ull);
#pragma unroll
      for (int q = 0; q < MAXROWS; ++q) {
        bool hA = (kkA != 0ull);
        int tA = hA ? __builtin_ctzll(kkA) : 0;
        if (hA) kkA &= kkA - 1;
        bqA[q] = hA ? (1ull << ((w - 1) * MAXROWS + tA)) : 0ull;
        LA[q] = 0; HA[q] = 0;
        if (hA) {
          const u64* rp = mb + (size_t)(cA * 64 + (w - 1) * MAXROWS + tA) * WPR;
          if (okLo) LA[q] = rp[l];
          if (okHi) HA[q] = rp[64 + l];
        }
        bool hB = (kkB != 0ull);
        int tB = hB ? __builtin_ctzll(kkB) : 0;
        if (hB) kkB &= kkB - 1;
        bqB[q] = hB ? (1ull << ((w - 1) * MAXROWS + tB)) : 0ull;
        LB[q] = 0; HB[q] = 0;
        if (hB) {
          const u64* rp = mb + (size_t)(cB * 64 + (w - 1) * MAXROWS + tB) * WPR;
          if (okLo) LB[q] = rp[l];
          if (okHi) HB[q] = rp[64 + l];
        }
      }
    }
    __syncthreads();                     // barrier A

    // ---------------- phase 2 (register/LDS only) ----------------
    if (w == 0) {
      u64 a1 = __ballot(nzcA != 0), b1 = __ballot(nzcB != 0);
      if (l == 0) { s_nzwA = a1; s_nzwB = b1; }
    } else {
      u64 kuA = s_kuA, kuB = s_kuB;
#pragma unroll
      for (int q = 0; q < MAXROWS; ++q) {
        if (kuA & bqA[q]) { plo |= LA[q]; phi |= HA[q]; }
        if (kuB & bqB[q]) { plo |= LB[q]; phi |= HB[q]; }
      }
      int wE = cA + 2, wO = cA + 3;
      u64 vE = (wE < 64) ? plo : phi;
      if (l == (wE & 63)) s_slotE[t & 1][w] = vE;
      u64 vO = (wO < 64) ? plo : phi;
      if (l == (wO & 63)) s_slotO[t & 1][w] = vO;
    }
    __syncthreads();                     // barrier B
  }

  // ---------------- fused output ----------------
  const float4* sbx = sboxes + (size_t)b * NB;
  const float* spb = sprob + (size_t)b * NB;
  for (int p = tid; p < NB; p += 512) {
    bool kp = false;
    if (p < K) {
      u64 wv = s_remv[p >> 6];
      kp = !((wv >> (p & 63)) & 1ull);
    }
    float4 bv = sbx[p];
    if (!kp) { bv.x = 0.0f; bv.y = 0.0f; bv.z = 0.0f; bv.w = 0.0f; }
    ((float4*)out)[(size_t)b * NB + p] = bv;
    out[(size_t)BIMG * NB * 4 + (size_t)b * NB + p] = kp ? spb[p] : 0.0f;
    out[(size_t)BIMG * NB * 5 + (size_t)b * NB + p] = kp ? 1.0f : 0.0f;
  }
}

// ---------------------------------------------------------------------------
// Fallback NMS kernel (used only if workspace is too small)
// ---------------------------------------------------------------------------
__global__ __launch_bounds__(1024) void nms_kernel(const float4* __restrict__ sboxes,
                                                   const float* __restrict__ sprob,
                                                   const u32* __restrict__ kcount,
                                                   float* __restrict__ out) {
  __shared__ float4 sb[NB];
  __shared__ unsigned char flag[NB];
  const int b = blockIdx.x;
  const int t = threadIdx.x;
  const int K = (int)kcount[b];

  for (int p = t; p < NB; p += 1024) {
    sb[p] = sboxes[(size_t)b * NB + p];
    flag[p] = (p < K) ? (unsigned char)0 : (unsigned char)1;
  }
  __syncthreads();

  for (int i = 0; i < K; ++i) {
    if (flag[i]) continue;
    float4 bi = sb[i];
    float area_i = (bi.z - bi.x) * (bi.w - bi.y);
    for (int j = i + 1 + t; j < K; j += 1024) {
      float4 bj = sb[j];
      float lx = fmaxf(bi.x, bj.x);
      float ly = fmaxf(bi.y, bj.y);
      float rx = fminf(bi.z, bj.z);
      float ry = fminf(bi.w, bj.w);
      float iw = fmaxf(rx - lx, 0.0f);
      float ih = fmaxf(ry - ly, 0.0f);
      float inter = iw * ih;
      float area_j = (bj.z - bj.x) * (bj.w - bj.y);
      float iou = inter / (area_i + area_j - inter);
      if (iou > 0.5f) flag[j] = (unsigned char)1;
    }
    __syncthreads();
  }

  float4* oboxes = (float4*)(out) + (size_t)b * NB;
  float* oscores = out + (size_t)BIMG * NB * 4 + (size_t)b * NB;
  float* okeep   = out + (size_t)BIMG * NB * 5 + (size_t)b * NB;
  for (int p = t; p < NB; p += 1024) {
    bool kp = (p < K) && (flag[p] == 0);
    float4 bv = sb[p];
    if (!kp) { bv.x = 0.0f; bv.y = 0.0f; bv.z = 0.0f; bv.w = 0.0f; }
    oboxes[p] = bv;
    oscores[p] = kp ? sprob[(size_t)b * NB + p] : 0.0f;
    okeep[p] = kp ? 1.0f : 0.0f;
  }
}

// ---------------------------------------------------------------------------
extern "C" void kernel_launch(void* const* d_in, const int* in_sizes, int n_in,
                              void* d_out, int out_size, void* d_ws, size_t ws_size,
                              hipStream_t stream) {
  const float* offsets = (const float*)d_in[0];   // [B,N,4] f32
  const float* labels  = (const float*)d_in[1];   // [B,N,1] f32
  const float* anchors = (const float*)d_in[2];   // [N,4]   f32
  float* out = (float*)d_out;

  char* ws = (char*)d_ws;
  u32*    kcount = (u32*)(ws + WS_KCOUNT);
  u64*    keys   = (u64*)(ws + WS_KEYS);
  float4* boxes  = (float4*)(ws + WS_BOXES);
  float*  prob   = (float*)(ws + WS_PROB);
  float4* sboxes = (float4*)(ws + WS_SBOXES);
  float*  sprob  = (float*)(ws + WS_SPROB);

  int total = BIMG * NB;
  decode_kernel<<<(total + 255) / 256, 256, 0, stream>>>(
      offsets, labels, anchors, keys, boxes, prob);

  rank_kernel<<<dim3(NB / 64, BIMG), 512, 0, stream>>>(
      keys, boxes, prob, sboxes, sprob, kcount);

  if (ws_size >= WS_NEEDED) {
    u64*    mask   = (u64*)(ws + WS_MASK);
    unsigned char* rownz = (unsigned char*)(ws + WS_ROWNZ);
    u64*    diag   = (u64*)(ws + WS_DIAG);
    u64*    diag2  = (u64*)(ws + WS_DIAG2);

    mask_kernel<<<dim3(NB / MROWS, BIMG), 256, 0, stream>>>(
        sboxes, kcount, mask, rownz, diag, diag2);

    scan_kernel<<<BIMG, 512, 0, stream>>>(mask, diag, diag2, rownz, kcount,
                                          sboxes, sprob, out);
  } else {
    nms_kernel<<<BIMG, 1024, 0, stream>>>(sboxes, sprob, kcount, out);
  }
}